// Round 5
// baseline (703.426 us; speedup 1.0000x reference)
//
#include <hip/hip_runtime.h>

// BipartiteGNN: 3-layer bipartite SAGEConv + global mean pool + linear.
// NS=NT=100000, E=1.6M per direction, F=H=64.
//
// R12: fuse gather + MFMA GEMM, occupancy-safe this time. R8's fusion died
// on 52.7KB LDS -> 23% occ; R11's split fgemm2 stayed latency-bound (~85µs
// vs ~15µs roofline, all pipes idle). This fused conv3 keeps 26.9KB LDS ->
// 6 blocks/CU = 75% occ (matches agg2's 76%) and caps VGPR at 85 via
// __launch_bounds__(256,6):
//  - weights staged to LDS [frag][lane] (16KB, lane-contiguous ds_read_b128,
//    conflict-free) instead of 64 VGPRs of register-resident frags;
//  - R7-proven gather writes bf16-packed means to a per-wave LDS tile that
//    IS the MFMA A-frag layout (lane lr reads uint4 at [lr][kg*4]);
//  - one barrier (weights+means visibility), 16 MFMAs/wave, barrier, then
//    C-stage reuses the dead weight-LDS region (R11-proven f32 transpose +
//    coalesced dwordx4 stores);
//  - A-array HBM round-trip eliminated (51MB/layer) + 1 dispatch/layer.
// Last layer keeps pooled epilogue (no Y write). CSR build / packs / final
// unchanged from R11.

#define FDIM 64

typedef short bh8 __attribute__((ext_vector_type(8)));  // 8 bf16 = 4 VGPR
typedef float fx4 __attribute__((ext_vector_type(4)));  // MFMA accumulator

__device__ __forceinline__ unsigned short f2bf(float f) {
  unsigned int u = __float_as_uint(f);
  unsigned int r = u + 0x7FFFu + ((u >> 16) & 1u);  // round-to-nearest-even
  return (unsigned short)(r >> 16);
}
__device__ __forceinline__ float bf2f(unsigned short h) {
  return __uint_as_float((unsigned int)h << 16);
}

// ---------------- CSR build (bucketed, atomic-free at global scope) ----------------
// Each pass handles BOTH directions in one dispatch (blockIdx selects).

__global__ __launch_bounds__(256) void hist2_kernel(const int* __restrict__ dstT,
                                                    int* __restrict__ HT, int NBT,
                                                    const int* __restrict__ dstS,
                                                    int* __restrict__ HS, int NBS,
                                                    int E, int B) {
  __shared__ int lh[512];
  int b = blockIdx.x;
  const int* dst;
  int* H;
  int NB;
  if (b < B) {
    dst = dstT; H = HT; NB = NBT;
  } else {
    b -= B; dst = dstS; H = HS; NB = NBS;
  }
  int t = threadIdx.x;
  lh[t] = 0;
  lh[t + 256] = 0;
  __syncthreads();
  int base = b * 4096;
#pragma unroll
  for (int i = 0; i < 16; ++i) {
    int e = base + i * 256 + t;
    if (e < E) atomicAdd(&lh[dst[e] >> 8], 1);
  }
  __syncthreads();
  int* row = H + (size_t)b * NB;
  if (t < NB) row[t] = lh[t];
  if (t + 256 < NB) row[t + 256] = lh[t + 256];
}

__global__ __launch_bounds__(256) void colscan2_kernel(int* __restrict__ HT,
                                                       int* __restrict__ totT, int NBT,
                                                       int* __restrict__ HS,
                                                       int* __restrict__ totS, int NBS,
                                                       int B) {
  __shared__ int sh[512];
  int k = blockIdx.x;
  int* H;
  int* tot;
  int NB;
  if (k < NBT) {
    H = HT; tot = totT; NB = NBT;
  } else {
    k -= NBT; H = HS; tot = totS; NB = NBS;
  }
  int t = threadIdx.x;
  int v0 = (t < B) ? H[(size_t)t * NB + k] : 0;
  int v1 = (t + 256 < B) ? H[(size_t)(t + 256) * NB + k] : 0;
  sh[t] = v0;
  sh[t + 256] = v1;
  __syncthreads();
  for (int d = 1; d < 512; d <<= 1) {
    int a0 = (t >= d) ? sh[t - d] : 0;
    int a1 = (t + 256 >= d) ? sh[t + 256 - d] : 0;
    __syncthreads();
    sh[t] += a0;
    sh[t + 256] += a1;
    __syncthreads();
  }
  if (t < B) H[(size_t)t * NB + k] = sh[t] - v0;  // exclusive
  if (t + 256 < B) H[(size_t)(t + 256) * NB + k] = sh[t + 256] - v1;
  if (t == 0) tot[k] = sh[511];
}

__global__ __launch_bounds__(256) void totscan2_kernel(const int* __restrict__ totT,
                                                       int* __restrict__ boffT, int NBT,
                                                       const int* __restrict__ totS,
                                                       int* __restrict__ boffS, int NBS) {
  __shared__ int sh[512];
  const int* tot = (blockIdx.x == 0) ? totT : totS;
  int* boff = (blockIdx.x == 0) ? boffT : boffS;
  int NB = (blockIdx.x == 0) ? NBT : NBS;
  int t = threadIdx.x;
  sh[t] = (t < NB) ? tot[t] : 0;
  sh[t + 256] = (t + 256 < NB) ? tot[t + 256] : 0;
  __syncthreads();
  for (int d = 1; d < 512; d <<= 1) {
    int a0 = (t >= d) ? sh[t - d] : 0;
    int a1 = (t + 256 >= d) ? sh[t + 256 - d] : 0;
    __syncthreads();
    sh[t] += a0;
    sh[t + 256] += a1;
    __syncthreads();
  }
  if (t < NB) boff[t] = (t > 0) ? sh[t - 1] : 0;
  if (t + 256 < NB) boff[t + 256] = sh[t + 255];
}

__global__ __launch_bounds__(256) void bin2_kernel(const int* __restrict__ srcT,
                                                   const int* __restrict__ dstT,
                                                   const int* __restrict__ HT,
                                                   const int* __restrict__ boffT,
                                                   int* __restrict__ binnedT, int NBT,
                                                   const int* __restrict__ srcS,
                                                   const int* __restrict__ dstS,
                                                   const int* __restrict__ HS,
                                                   const int* __restrict__ boffS,
                                                   int* __restrict__ binnedS, int NBS,
                                                   int E, int B) {
  __shared__ int cur[512];
  int b = blockIdx.x;
  const int *src, *dst, *H, *boff;
  int* binned;
  int NB;
  if (b < B) {
    src = srcT; dst = dstT; H = HT; boff = boffT; binned = binnedT; NB = NBT;
  } else {
    b -= B; src = srcS; dst = dstS; H = HS; boff = boffS; binned = binnedS; NB = NBS;
  }
  int t = threadIdx.x;
  const int* row = H + (size_t)b * NB;
  if (t < NB) cur[t] = row[t] + boff[t];
  if (t + 256 < NB) cur[t + 256] = row[t + 256] + boff[t + 256];
  __syncthreads();
  int base = b * 4096;
#pragma unroll
  for (int i = 0; i < 16; ++i) {
    int e = base + i * 256 + t;
    if (e < E) {
      int d = dst[e];
      int p = atomicAdd(&cur[d >> 8], 1);  // LDS atomic
      binned[p] = (src[e] << 8) | (d & 255);
    }
  }
}

__global__ __launch_bounds__(256) void build2_kernel(const int* __restrict__ binnedT,
                                                     const int* __restrict__ boffT,
                                                     int* __restrict__ offT,
                                                     int* __restrict__ csrT,
                                                     float* __restrict__ invT,
                                                     int NT, int NBT,
                                                     const int* __restrict__ binnedS,
                                                     const int* __restrict__ boffS,
                                                     int* __restrict__ offS,
                                                     int* __restrict__ csrS,
                                                     float* __restrict__ invS,
                                                     int NS, int NBS, int E) {
  __shared__ int cnt[256];
  __shared__ int lofs[256];
  __shared__ int cur[256];
  int b = blockIdx.x;
  const int *binned, *boff;
  int *off, *csr;
  float* inv_deg;
  int N, NB;
  if (b < NBT) {
    binned = binnedT; boff = boffT; off = offT; csr = csrT; inv_deg = invT;
    N = NT; NB = NBT;
  } else {
    b -= NBT;
    binned = binnedS; boff = boffS; off = offS; csr = csrS; inv_deg = invS;
    N = NS; NB = NBS;
  }
  int t = threadIdx.x;
  int n0 = b << 8;
  cnt[t] = 0;
  __syncthreads();
  int s0 = boff[b];
  int s1 = (b + 1 < NB) ? boff[b + 1] : E;
  for (int i = s0 + t; i < s1; i += 256) {
    atomicAdd(&cnt[binned[i] & 255], 1);  // LDS atomic
  }
  __syncthreads();
  int c = cnt[t];
  lofs[t] = c;
  __syncthreads();
  for (int d = 1; d < 256; d <<= 1) {
    int v = (t >= d) ? lofs[t - d] : 0;
    __syncthreads();
    lofs[t] += v;
    __syncthreads();
  }
  int excl = lofs[t] - c;
  cur[t] = s0 + excl;
  int node = n0 + t;
  if (node < N) {
    off[node] = s0 + excl;
    inv_deg[node] = 1.0f / (float)max(c, 1);
    if (node == N - 1) off[N] = s0 + excl + c;
  }
  __syncthreads();
  for (int i = s0 + t; i < s1; i += 256) {
    int e = binned[i];
    int r = atomicAdd(&cur[e & 255], 1);  // LDS atomic
    csr[r] = e >> 8;
  }
}

// ---------------- fp32 -> bf16 pack ----------------

__global__ void pack_kernel(const float* __restrict__ X, unsigned short* __restrict__ Y, int n4) {
  int i = blockIdx.x * 256 + threadIdx.x;
  if (i < n4) {
    float4 v = ((const float4*)X)[i];
    uint2 pk;
    pk.x = (unsigned int)f2bf(v.x) | ((unsigned int)f2bf(v.y) << 16);
    pk.y = (unsigned int)f2bf(v.z) | ((unsigned int)f2bf(v.w) << 16);
    ((uint2*)Y)[i] = pk;
  }
}

__global__ void pack4_kernel(const float* __restrict__ X0, unsigned short* __restrict__ Y0,
                             const float* __restrict__ X1, unsigned short* __restrict__ Y1,
                             const float* __restrict__ X2, unsigned short* __restrict__ Y2,
                             const float* __restrict__ X3, unsigned short* __restrict__ Y3,
                             int n4, int gPer) {
  int seg = blockIdx.x / gPer;
  int i = (blockIdx.x - seg * gPer) * 256 + threadIdx.x;
  const float* X = (seg == 0) ? X0 : (seg == 1) ? X1 : (seg == 2) ? X2 : X3;
  unsigned short* Y = (seg == 0) ? Y0 : (seg == 1) ? Y1 : (seg == 2) ? Y2 : Y3;
  if (i < n4) {
    float4 v = ((const float4*)X)[i];
    uint2 pk;
    pk.x = (unsigned int)f2bf(v.x) | ((unsigned int)f2bf(v.y) << 16);
    pk.y = (unsigned int)f2bf(v.z) | ((unsigned int)f2bf(v.w) << 16);
    ((uint2*)Y)[i] = pk;
  }
}

// ---------------- fused conv3: gather-mean -> MFMA dual GEMM -> store/pool ----------------
// Block = 4 waves, 64 dst nodes (16/wave). LDS: cst 17.4KB (weight frags,
// then reused for C staging) + msh 9.2KB (bf16 means, A-frag layout) +
// pacc = 26.9KB -> 6 blocks/CU (75% occ). VGPR capped 85 by launch_bounds.

__global__ __launch_bounds__(256, 6) void conv3_kernel(
    const unsigned short* __restrict__ Msg1, const unsigned short* __restrict__ Xd1,
    const int* __restrict__ off1, const int* __restrict__ csr1,
    const unsigned short* __restrict__ Wl1, const unsigned short* __restrict__ Wr1,
    const float* __restrict__ bias1, unsigned short* __restrict__ Y1, int N1,
    const unsigned short* __restrict__ Msg2, const unsigned short* __restrict__ Xd2,
    const int* __restrict__ off2, const int* __restrict__ csr2,
    const unsigned short* __restrict__ Wl2, const unsigned short* __restrict__ Wr2,
    const float* __restrict__ bias2, unsigned short* __restrict__ Y2, int N2,
    int g1, float* __restrict__ pooled, int lastLayer) {
  __shared__ __align__(16) float cst[4][16][68];         // 17.4KB: wlds union / C-stage
  __shared__ __align__(16) unsigned int msh[4][16][36];  // 9.2KB: bf16-packed means
  __shared__ float pacc[64];
  uint4* wlds = (uint4*)&cst[0][0][0];  // wlds[f*64 + lane], f = op*8 + half*4 + nt

  int bid = blockIdx.x;
  const unsigned short *Msg, *Xd, *Wlb, *Wrb;
  const int *off, *csr;
  const float* bias;
  unsigned short* Y;
  int N;
  if (bid < g1) {
    Msg = Msg1; Xd = Xd1; off = off1; csr = csr1; Wlb = Wl1; Wrb = Wr1;
    bias = bias1; Y = Y1; N = N1;
  } else {
    bid -= g1;
    Msg = Msg2; Xd = Xd2; off = off2; csr = csr2; Wlb = Wl2; Wrb = Wr2;
    bias = bias2; Y = Y2; N = N2;
  }
  int t = threadIdx.x;
  if (lastLayer && t < 64) pacc[t] = 0.f;

  // stage weight frags to LDS: frag f lane l holds W[row=(f&3)*16+(l&15)]
  // elems ((f>>2)&1)*32 + (l>>4)*8 .. +8  (16B). Read back lane-contiguous.
  for (int i = t; i < 1024; i += 256) {
    int f = i >> 6, l = i & 63;
    const unsigned short* W = (f & 8) ? Wrb : Wlb;
    int row = (f & 3) * 16 + (l & 15);
    int ce = ((f >> 2) & 1) * 32 + (l >> 4) * 8;
    wlds[f * 64 + l] = *(const uint4*)(W + row * 64 + ce);
  }

  int wid = t >> 6, lane = t & 63;
  int g = lane >> 4;    // gather edge group 0..3
  int fl = lane & 15;   // gather feature sublane (feats fl*4..fl*4+4)
  int n0 = (bid << 6) + (wid << 4);  // this wave's first node

  // prefetch this wave's 17 CSR offsets
  int oi = n0 + ((lane < 17) ? lane : 16);
  int offv = off[min(oi, N)];

  // ---- gather phase (R7-proven pattern), means -> msh in A-frag layout ----
  for (int i = 0; i < 16; ++i) {
    int s0 = __shfl(offv, i, 64);      // wave-uniform
    int s1 = __shfl(offv, i + 1, 64);  // node >= N => s0 == s1
    float ax = 0.f, ay = 0.f, az = 0.f, aw = 0.f;
    for (int base = s0; base < s1; base += 64) {
      int idx = base + lane;
      int mysrc = (idx < s1) ? csr[idx] : 0;
      int m = min(64, s1 - base);
      int kmax = (m + 3) >> 2;  // wave-uniform
      for (int k = 0; k < kmax; ++k) {
        int j = g + 4 * k;
        int s = __shfl(mysrc, (j < m) ? j : 0, 64);  // all 64 lanes active
        if (j < m) {
          uint2 v = *((const uint2*)(Msg + (size_t)s * 64) + fl);
          ax += bf2f((unsigned short)(v.x & 0xffffu));
          ay += bf2f((unsigned short)(v.x >> 16));
          az += bf2f((unsigned short)(v.y & 0xffffu));
          aw += bf2f((unsigned short)(v.y >> 16));
        }
      }
    }
    ax += __shfl_down(ax, 32, 64); ay += __shfl_down(ay, 32, 64);
    az += __shfl_down(az, 32, 64); aw += __shfl_down(aw, 32, 64);
    ax += __shfl_down(ax, 16, 64); ay += __shfl_down(ay, 16, 64);
    az += __shfl_down(az, 16, 64); aw += __shfl_down(aw, 16, 64);
    if (g == 0) {
      float id = (s1 > s0) ? 1.0f / (float)(s1 - s0) : 0.f;
      uint2 pk;
      pk.x = (unsigned int)f2bf(ax * id) | ((unsigned int)f2bf(ay * id) << 16);
      pk.y = (unsigned int)f2bf(az * id) | ((unsigned int)f2bf(aw * id) << 16);
      *((uint2*)&msh[wid][i][fl * 2]) = pk;
    }
  }

  // issue Xd row loads early; consumed after the barrier
  int lr = fl;  // row within frags; col (=h low bits) within C
  int kg = g;   // k-subgroup 0..3
  int mr = min(n0 + lr, N - 1);
  const bh8* xrow = (const bh8*)(Xd + (size_t)mr * 64);
  bh8 x0 = xrow[kg], x1 = xrow[4 + kg];

  __syncthreads();  // weights + means visible to all waves

  union UB { uint4 u; bh8 v; };
  UB ua0, ua1;
  ua0.u = *(const uint4*)&msh[wid][lr][kg * 4];       // feats kg*8..+8
  ua1.u = *(const uint4*)&msh[wid][lr][16 + kg * 4];  // feats 32+kg*8..+8

  float bias_r[4];
#pragma unroll
  for (int nt = 0; nt < 4; ++nt) bias_r[nt] = bias[nt * 16 + lr];

  fx4 acc[4];
#pragma unroll
  for (int nt = 0; nt < 4; ++nt) acc[nt] = (fx4){0.f, 0.f, 0.f, 0.f};
#pragma unroll
  for (int nt = 0; nt < 4; ++nt) {
    UB b0, b1, b2, b3;
    b0.u = wlds[nt * 64 + lane];          // Wl k 0..31
    b1.u = wlds[(4 + nt) * 64 + lane];    // Wl k 32..63
    b2.u = wlds[(8 + nt) * 64 + lane];    // Wr k 0..31
    b3.u = wlds[(12 + nt) * 64 + lane];   // Wr k 32..63
    acc[nt] = __builtin_amdgcn_mfma_f32_16x16x32_bf16(ua0.v, b0.v, acc[nt], 0, 0, 0);
    acc[nt] = __builtin_amdgcn_mfma_f32_16x16x32_bf16(ua1.v, b1.v, acc[nt], 0, 0, 0);
    acc[nt] = __builtin_amdgcn_mfma_f32_16x16x32_bf16(x0, b2.v, acc[nt], 0, 0, 0);
    acc[nt] = __builtin_amdgcn_mfma_f32_16x16x32_bf16(x1, b3.v, acc[nt], 0, 0, 0);
  }

  __syncthreads();  // all frag reads done -> wlds region reusable as cst

  if (!lastLayer) {
    // stage C (bias added) into per-wave tile: row = kg*4+j, col = h
#pragma unroll
    for (int nt = 0; nt < 4; ++nt)
#pragma unroll
      for (int j = 0; j < 4; ++j)
        cst[wid][kg * 4 + j][nt * 16 + lr] = acc[nt][j] + bias_r[nt];
    // per-wave tile readback (R11-proven, no extra barrier needed)
#pragma unroll
    for (int s = 0; s < 2; ++s) {
      int idx = lane + 64 * s;  // 16 rows x 8 chunks of 8 h
      int r = idx >> 3, c = idx & 7;
      float4 v0 = *(const float4*)&cst[wid][r][c * 8];
      float4 v1 = *(const float4*)&cst[wid][r][c * 8 + 4];
      uint4 pk;
      pk.x = (unsigned int)f2bf(v0.x) | ((unsigned int)f2bf(v0.y) << 16);
      pk.y = (unsigned int)f2bf(v0.z) | ((unsigned int)f2bf(v0.w) << 16);
      pk.z = (unsigned int)f2bf(v1.x) | ((unsigned int)f2bf(v1.y) << 16);
      pk.w = (unsigned int)f2bf(v1.z) | ((unsigned int)f2bf(v1.w) << 16);
      int m = n0 + r;
      if (m < N) ((uint4*)(Y + (size_t)m * 64))[c] = pk;
    }
  } else {
    // last layer feeds only global mean pool: no Y write
    float psum[4];
#pragma unroll
    for (int nt = 0; nt < 4; ++nt) {
      float sacc = 0.f;
#pragma unroll
      for (int j = 0; j < 4; ++j) {
        int m = n0 + kg * 4 + j;
        if (m < N) sacc += acc[nt][j] + bias_r[nt];
      }
      psum[nt] = sacc;
    }
#pragma unroll
    for (int nt = 0; nt < 4; ++nt) atomicAdd(&pacc[nt * 16 + lr], psum[nt]);
    __syncthreads();
    if (t < 64) atomicAdd(&pooled[t], pacc[t]);
  }
}

// ---------------- final linear ----------------

__global__ void final_kernel(const float* __restrict__ pooled, const float* __restrict__ linW,
                             const float* __restrict__ linb, float* __restrict__ out, float invM) {
  int t = threadIdx.x;  // 64 threads
  float v = pooled[t] * invM * linW[t];
#pragma unroll
  for (int o = 32; o > 0; o >>= 1) v += __shfl_down(v, o, 64);
  if (t == 0) out[0] = v + linb[0];
}

// ---------------- launch ----------------

extern "C" void kernel_launch(void* const* d_in, const int* in_sizes, int n_in,
                              void* d_out, int out_size, void* d_ws, size_t ws_size,
                              hipStream_t stream) {
  const float* x_source = (const float*)d_in[0];
  const float* x_target = (const float*)d_in[1];
  float* scratchA = (float*)d_in[2];  // edge_attr_s2t: 12.8M floats, unused input
  float* scratchB = (float*)d_in[3];  // edge_attr_t2s: 12.8M floats, unused input
  const float* W_l_s2t = (const float*)d_in[4];
  const float* b_s2t   = (const float*)d_in[5];
  const float* W_r_s2t = (const float*)d_in[6];
  const float* W_l_t2s = (const float*)d_in[7];
  const float* b_t2s   = (const float*)d_in[8];
  const float* W_r_t2s = (const float*)d_in[9];
  const float* lin_W   = (const float*)d_in[10];
  const float* lin_b   = (const float*)d_in[11];
  const int* ei_s2t    = (const int*)d_in[12];
  const int* ei_t2s    = (const int*)d_in[13];

  const int NS = in_sizes[0] / FDIM;
  const int NT = in_sizes[1] / FDIM;
  const int E  = in_sizes[12] / 2;
  const int L  = in_sizes[4] / (FDIM * FDIM);
  const size_t NF = (size_t)NS * FDIM;        // 6.4M elems
  const size_t WN = (size_t)L * FDIM * FDIM;  // per weight array, elems

  // scratchA: S0, T0 (bf16 NF), Wb x4, csr_t, csr_s, inv_t, inv_s, off_t, off_s
  unsigned short* S0 = (unsigned short*)scratchA;          // NF bf16
  unsigned short* T0 = S0 + NF;                            // NF bf16
  unsigned short* WbLs2t = T0 + NF;                        // L*4096 bf16
  unsigned short* WbRs2t = WbLs2t + WN;
  unsigned short* WbLt2s = WbRs2t + WN;
  unsigned short* WbRt2s = WbLt2s + WN;
  int*   csr_t  = (int*)(WbRt2s + WN);        // E
  int*   csr_s  = csr_t + E;                  // E
  float* inv_t  = (float*)(csr_s + E);        // NS
  float* inv_s  = inv_t + NS;                 // NS
  int*   off_t  = (int*)(inv_s + NS);         // NS+1
  int*   off_s  = off_t + NS + 1;             // NS+1

  const int NB_T = (NT + 255) >> 8;
  const int NB_S = (NS + 255) >> 8;
  const int B    = (E + 4095) >> 12;

  // scratchB: S1, T1, binned_t, binned_s, H_t, H_s, tot/boff x2
  unsigned short* S1 = (unsigned short*)scratchB;          // NF bf16
  unsigned short* T1 = S1 + NF;                            // NF bf16
  int* binned_t = (int*)(T1 + NF);                         // E
  int* binned_s = binned_t + E;                            // E
  int* H_t      = binned_s + E;                            // B*NB_T
  int* H_s      = H_t + (size_t)B * NB_T;                  // B*NB_S
  int* tot_t    = H_s + (size_t)B * NB_S;                  // 512
  int* boff_t   = tot_t + 512;                             // 512
  int* tot_s    = boff_t + 512;                            // 512
  int* boff_s   = tot_s + 512;                             // 512

  // d_ws: pooled
  float* pooled = (float*)d_ws;

  const int* src_s2t = ei_s2t;
  const int* dst_s2t = ei_s2t + E;
  const int* src_t2s = ei_t2s;
  const int* dst_t2s = ei_t2s + E;

  // --- CSR build, both directions per pass ---
  hist2_kernel<<<2 * B, 256, 0, stream>>>(dst_s2t, H_t, NB_T, dst_t2s, H_s, NB_S, E, B);
  colscan2_kernel<<<NB_T + NB_S, 256, 0, stream>>>(H_t, tot_t, NB_T, H_s, tot_s, NB_S, B);
  totscan2_kernel<<<2, 256, 0, stream>>>(tot_t, boff_t, NB_T, tot_s, boff_s, NB_S);
  bin2_kernel<<<2 * B, 256, 0, stream>>>(src_s2t, dst_s2t, H_t, boff_t, binned_t, NB_T,
                                         src_t2s, dst_t2s, H_s, boff_s, binned_s, NB_S, E, B);
  build2_kernel<<<NB_T + NB_S, 256, 0, stream>>>(binned_t, boff_t, off_t, csr_t, inv_t, NT, NB_T,
                                                 binned_s, boff_s, off_s, csr_s, inv_s, NS, NB_S, E);

  // --- bf16 packs: features (2 dispatches) + all weights (1 dispatch) ---
  int gP = (int)((NF / 4 + 255) / 256);
  pack_kernel<<<gP, 256, 0, stream>>>(x_source, S0, (int)(NF / 4));
  pack_kernel<<<gP, 256, 0, stream>>>(x_target, T0, (int)(NF / 4));
  int n4W = (int)(WN / 4);
  int gW = (n4W + 255) / 256;
  pack4_kernel<<<4 * gW, 256, 0, stream>>>(W_l_s2t, WbLs2t, W_r_s2t, WbRs2t,
                                           W_l_t2s, WbLt2s, W_r_t2s, WbRt2s, n4W, gW);

  hipMemsetAsync(pooled, 0, 64 * 4, stream);

  unsigned short* xs_in = S0;
  unsigned short* xt_in = T0;
  unsigned short* xs_out = S1;
  unsigned short* xt_out = T1;

  int gT3 = (NT + 63) / 64;  // conv3 blocks per direction (64 nodes/block)
  int gS3 = (NS + 63) / 64;

  for (int l = 0; l < L; ++l) {
    const unsigned short* Wl1 = WbLs2t + (size_t)l * 4096;
    const unsigned short* Wr1 = WbRs2t + (size_t)l * 4096;
    const float* bb1 = b_s2t + (size_t)l * 64;
    const unsigned short* Wl2 = WbLt2s + (size_t)l * 4096;
    const unsigned short* Wr2 = WbRt2s + (size_t)l * 4096;
    const float* bb2 = b_t2s + (size_t)l * 64;
    int last = (l == L - 1) ? 1 : 0;

    // dir1: xt_out = mean_agg(xs_in)@Wl1^T + xt_in@Wr1^T + b1
    // dir2: xs_out = mean_agg(xt_in)@Wl2^T + xs_in@Wr2^T + b2
    conv3_kernel<<<gT3 + gS3, 256, 0, stream>>>(
        xs_in, xt_in, off_t, csr_t, Wl1, Wr1, bb1, xt_out, NT,
        xt_in, xs_in, off_s, csr_s, Wl2, Wr2, bb2, xs_out, NS,
        gT3, pooled, last);

    unsigned short* ts = xs_in; xs_in = xs_out; xs_out = ts;
    unsigned short* tt = xt_in; xt_in = xt_out; xt_out = tt;
  }

  final_kernel<<<1, 64, 0, stream>>>(pooled, lin_W, lin_b, (float*)d_out,
                                     1.0f / (float)(NS + NT));
}

// Round 6
// 617.773 us; speedup vs baseline: 1.1386x; 1.1386x over previous
//
#include <hip/hip_runtime.h>

// BipartiteGNN: 3-layer bipartite SAGEConv + global mean pool + linear.
// NS=NT=100000, E=1.6M per direction, F=H=64.
//
// R13: revert to R11's split structure (best, 649 µs; two fusion attempts
// both starved the gather — agg2 stays standalone). Rewrite the GEMM only.
// R10/R11's MFMA GEMM idled at ~54 µs/dir (Mfma 1%, VALU 2%, FETCH 12.6MB
// = L3-warm): every wave re-read the SAME 16KB of weights via 64-lane
// scattered 16B loads -> ~6.4M requests hot-spotting 128 cache lines ->
// all waves serialized on a few L2 banks (invisible in SQ counters).
// fgemm3 fixes:
//  - block loads Wl||Wr ONCE with fully-coalesced linear uint4 reads
//    (4/thread), writes LDS pre-permuted so B-frag f = wlds[f*64+lane]
//    -> frag reads are lane-contiguous ds_read_b128 (conflict-free);
//  - 256 rows/block (4 waves x 4 subtiles): weight traffic 100MB -> 12.5MB
//    per dispatch; 16 frags stay in registers across subtiles;
//  - next-subtile A/X prefetch under current MFMAs; R11-proven cst
//    transpose -> coalesced dwordx4 Y stores; pooled epilogue last layer.
// agg2 / CSR build / packs unchanged from R11.

#define FDIM 64

typedef short bh8 __attribute__((ext_vector_type(8)));  // 8 bf16 = 4 VGPR
typedef float fx4 __attribute__((ext_vector_type(4)));  // MFMA accumulator

__device__ __forceinline__ unsigned short f2bf(float f) {
  unsigned int u = __float_as_uint(f);
  unsigned int r = u + 0x7FFFu + ((u >> 16) & 1u);  // round-to-nearest-even
  return (unsigned short)(r >> 16);
}
__device__ __forceinline__ float bf2f(unsigned short h) {
  return __uint_as_float((unsigned int)h << 16);
}

// ---------------- CSR build (bucketed, atomic-free at global scope) ----------------
// Each pass handles BOTH directions in one dispatch (blockIdx selects).

__global__ __launch_bounds__(256) void hist2_kernel(const int* __restrict__ dstT,
                                                    int* __restrict__ HT, int NBT,
                                                    const int* __restrict__ dstS,
                                                    int* __restrict__ HS, int NBS,
                                                    int E, int B) {
  __shared__ int lh[512];
  int b = blockIdx.x;
  const int* dst;
  int* H;
  int NB;
  if (b < B) {
    dst = dstT; H = HT; NB = NBT;
  } else {
    b -= B; dst = dstS; H = HS; NB = NBS;
  }
  int t = threadIdx.x;
  lh[t] = 0;
  lh[t + 256] = 0;
  __syncthreads();
  int base = b * 4096;
#pragma unroll
  for (int i = 0; i < 16; ++i) {
    int e = base + i * 256 + t;
    if (e < E) atomicAdd(&lh[dst[e] >> 8], 1);
  }
  __syncthreads();
  int* row = H + (size_t)b * NB;
  if (t < NB) row[t] = lh[t];
  if (t + 256 < NB) row[t + 256] = lh[t + 256];
}

__global__ __launch_bounds__(256) void colscan2_kernel(int* __restrict__ HT,
                                                       int* __restrict__ totT, int NBT,
                                                       int* __restrict__ HS,
                                                       int* __restrict__ totS, int NBS,
                                                       int B) {
  __shared__ int sh[512];
  int k = blockIdx.x;
  int* H;
  int* tot;
  int NB;
  if (k < NBT) {
    H = HT; tot = totT; NB = NBT;
  } else {
    k -= NBT; H = HS; tot = totS; NB = NBS;
  }
  int t = threadIdx.x;
  int v0 = (t < B) ? H[(size_t)t * NB + k] : 0;
  int v1 = (t + 256 < B) ? H[(size_t)(t + 256) * NB + k] : 0;
  sh[t] = v0;
  sh[t + 256] = v1;
  __syncthreads();
  for (int d = 1; d < 512; d <<= 1) {
    int a0 = (t >= d) ? sh[t - d] : 0;
    int a1 = (t + 256 >= d) ? sh[t + 256 - d] : 0;
    __syncthreads();
    sh[t] += a0;
    sh[t + 256] += a1;
    __syncthreads();
  }
  if (t < B) H[(size_t)t * NB + k] = sh[t] - v0;  // exclusive
  if (t + 256 < B) H[(size_t)(t + 256) * NB + k] = sh[t + 256] - v1;
  if (t == 0) tot[k] = sh[511];
}

__global__ __launch_bounds__(256) void totscan2_kernel(const int* __restrict__ totT,
                                                       int* __restrict__ boffT, int NBT,
                                                       const int* __restrict__ totS,
                                                       int* __restrict__ boffS, int NBS) {
  __shared__ int sh[512];
  const int* tot = (blockIdx.x == 0) ? totT : totS;
  int* boff = (blockIdx.x == 0) ? boffT : boffS;
  int NB = (blockIdx.x == 0) ? NBT : NBS;
  int t = threadIdx.x;
  sh[t] = (t < NB) ? tot[t] : 0;
  sh[t + 256] = (t + 256 < NB) ? tot[t + 256] : 0;
  __syncthreads();
  for (int d = 1; d < 512; d <<= 1) {
    int a0 = (t >= d) ? sh[t - d] : 0;
    int a1 = (t + 256 >= d) ? sh[t + 256 - d] : 0;
    __syncthreads();
    sh[t] += a0;
    sh[t + 256] += a1;
    __syncthreads();
  }
  if (t < NB) boff[t] = (t > 0) ? sh[t - 1] : 0;
  if (t + 256 < NB) boff[t + 256] = sh[t + 255];
}

__global__ __launch_bounds__(256) void bin2_kernel(const int* __restrict__ srcT,
                                                   const int* __restrict__ dstT,
                                                   const int* __restrict__ HT,
                                                   const int* __restrict__ boffT,
                                                   int* __restrict__ binnedT, int NBT,
                                                   const int* __restrict__ srcS,
                                                   const int* __restrict__ dstS,
                                                   const int* __restrict__ HS,
                                                   const int* __restrict__ boffS,
                                                   int* __restrict__ binnedS, int NBS,
                                                   int E, int B) {
  __shared__ int cur[512];
  int b = blockIdx.x;
  const int *src, *dst, *H, *boff;
  int* binned;
  int NB;
  if (b < B) {
    src = srcT; dst = dstT; H = HT; boff = boffT; binned = binnedT; NB = NBT;
  } else {
    b -= B; src = srcS; dst = dstS; H = HS; boff = boffS; binned = binnedS; NB = NBS;
  }
  int t = threadIdx.x;
  const int* row = H + (size_t)b * NB;
  if (t < NB) cur[t] = row[t] + boff[t];
  if (t + 256 < NB) cur[t + 256] = row[t + 256] + boff[t + 256];
  __syncthreads();
  int base = b * 4096;
#pragma unroll
  for (int i = 0; i < 16; ++i) {
    int e = base + i * 256 + t;
    if (e < E) {
      int d = dst[e];
      int p = atomicAdd(&cur[d >> 8], 1);  // LDS atomic
      binned[p] = (src[e] << 8) | (d & 255);
    }
  }
}

__global__ __launch_bounds__(256) void build2_kernel(const int* __restrict__ binnedT,
                                                     const int* __restrict__ boffT,
                                                     int* __restrict__ offT,
                                                     int* __restrict__ csrT,
                                                     float* __restrict__ invT,
                                                     int NT, int NBT,
                                                     const int* __restrict__ binnedS,
                                                     const int* __restrict__ boffS,
                                                     int* __restrict__ offS,
                                                     int* __restrict__ csrS,
                                                     float* __restrict__ invS,
                                                     int NS, int NBS, int E) {
  __shared__ int cnt[256];
  __shared__ int lofs[256];
  __shared__ int cur[256];
  int b = blockIdx.x;
  const int *binned, *boff;
  int *off, *csr;
  float* inv_deg;
  int N, NB;
  if (b < NBT) {
    binned = binnedT; boff = boffT; off = offT; csr = csrT; inv_deg = invT;
    N = NT; NB = NBT;
  } else {
    b -= NBT;
    binned = binnedS; boff = boffS; off = offS; csr = csrS; inv_deg = invS;
    N = NS; NB = NBS;
  }
  int t = threadIdx.x;
  int n0 = b << 8;
  cnt[t] = 0;
  __syncthreads();
  int s0 = boff[b];
  int s1 = (b + 1 < NB) ? boff[b + 1] : E;
  for (int i = s0 + t; i < s1; i += 256) {
    atomicAdd(&cnt[binned[i] & 255], 1);  // LDS atomic
  }
  __syncthreads();
  int c = cnt[t];
  lofs[t] = c;
  __syncthreads();
  for (int d = 1; d < 256; d <<= 1) {
    int v = (t >= d) ? lofs[t - d] : 0;
    __syncthreads();
    lofs[t] += v;
    __syncthreads();
  }
  int excl = lofs[t] - c;
  cur[t] = s0 + excl;
  int node = n0 + t;
  if (node < N) {
    off[node] = s0 + excl;
    inv_deg[node] = 1.0f / (float)max(c, 1);
    if (node == N - 1) off[N] = s0 + excl + c;
  }
  __syncthreads();
  for (int i = s0 + t; i < s1; i += 256) {
    int e = binned[i];
    int r = atomicAdd(&cur[e & 255], 1);  // LDS atomic
    csr[r] = e >> 8;
  }
}

// ---------------- fp32 -> bf16 pack ----------------

__global__ void pack_kernel(const float* __restrict__ X, unsigned short* __restrict__ Y, int n4) {
  int i = blockIdx.x * 256 + threadIdx.x;
  if (i < n4) {
    float4 v = ((const float4*)X)[i];
    uint2 pk;
    pk.x = (unsigned int)f2bf(v.x) | ((unsigned int)f2bf(v.y) << 16);
    pk.y = (unsigned int)f2bf(v.z) | ((unsigned int)f2bf(v.w) << 16);
    ((uint2*)Y)[i] = pk;
  }
}

__global__ void pack4_kernel(const float* __restrict__ X0, unsigned short* __restrict__ Y0,
                             const float* __restrict__ X1, unsigned short* __restrict__ Y1,
                             const float* __restrict__ X2, unsigned short* __restrict__ Y2,
                             const float* __restrict__ X3, unsigned short* __restrict__ Y3,
                             int n4, int gPer) {
  int seg = blockIdx.x / gPer;
  int i = (blockIdx.x - seg * gPer) * 256 + threadIdx.x;
  const float* X = (seg == 0) ? X0 : (seg == 1) ? X1 : (seg == 2) ? X2 : X3;
  unsigned short* Y = (seg == 0) ? Y0 : (seg == 1) ? Y1 : (seg == 2) ? Y2 : Y3;
  if (i < n4) {
    float4 v = ((const float4*)X)[i];
    uint2 pk;
    pk.x = (unsigned int)f2bf(v.x) | ((unsigned int)f2bf(v.y) << 16);
    pk.y = (unsigned int)f2bf(v.z) | ((unsigned int)f2bf(v.w) << 16);
    ((uint2*)Y)[i] = pk;
  }
}

// ---------------- aggregation (both directions, one dispatch) ----------------
// R7-proven body: one wave per dst node; 4 groups of 16 lanes, uint2 loads,
// wave-uniform inner trip count (every __shfl sees all 64 lanes active).
// Measured: 97.6 µs merged, 2.0 TB/s, occ 76%.

__global__ __launch_bounds__(256) void agg2_kernel(
    const unsigned short* __restrict__ MsgT, const int* __restrict__ offT,
    const int* __restrict__ csrT, const float* __restrict__ invT,
    unsigned short* __restrict__ AT, int NT, int gT,
    const unsigned short* __restrict__ MsgS, const int* __restrict__ offS,
    const int* __restrict__ csrS, const float* __restrict__ invS,
    unsigned short* __restrict__ AS, int NS) {
  int b = blockIdx.x;
  const unsigned short* Msg;
  const int *off, *csr;
  const float* inv_deg;
  unsigned short* A;
  int N;
  if (b < gT) {
    Msg = MsgT; off = offT; csr = csrT; inv_deg = invT; A = AT; N = NT;
  } else {
    b -= gT;
    Msg = MsgS; off = offS; csr = csrS; inv_deg = invS; A = AS; N = NS;
  }
  int w = (b * 256 + threadIdx.x) >> 6;
  int lane = threadIdx.x & 63;
  if (w >= N) return;
  int g = lane >> 4;    // edge group 0..3
  int fl = lane & 15;   // feature sublane: features [fl*4, fl*4+4)
  int s0 = off[w], s1 = off[w + 1];
  float ax = 0.f, ay = 0.f, az = 0.f, aw = 0.f;
  for (int base = s0; base < s1; base += 64) {
    int idx = base + lane;
    int mysrc = (idx < s1) ? csr[idx] : 0;
    int m = min(64, s1 - base);
    int kmax = (m + 3) >> 2;  // wave-uniform
    for (int k = 0; k < kmax; ++k) {
      int j = g + 4 * k;
      int s = __shfl(mysrc, (j < m) ? j : 0, 64);  // all 64 lanes active here
      if (j < m) {
        uint2 v = *((const uint2*)(Msg + (size_t)s * 64) + fl);
        ax += bf2f((unsigned short)(v.x & 0xffffu));
        ay += bf2f((unsigned short)(v.x >> 16));
        az += bf2f((unsigned short)(v.y & 0xffffu));
        aw += bf2f((unsigned short)(v.y >> 16));
      }
    }
  }
  ax += __shfl_down(ax, 32, 64);
  ay += __shfl_down(ay, 32, 64);
  az += __shfl_down(az, 32, 64);
  aw += __shfl_down(aw, 32, 64);
  ax += __shfl_down(ax, 16, 64);
  ay += __shfl_down(ay, 16, 64);
  az += __shfl_down(az, 16, 64);
  aw += __shfl_down(aw, 16, 64);
  if (g == 0) {
    float id = inv_deg[w];
    uint2 pk;
    pk.x = (unsigned int)f2bf(ax * id) | ((unsigned int)f2bf(ay * id) << 16);
    pk.y = (unsigned int)f2bf(az * id) | ((unsigned int)f2bf(aw * id) << 16);
    *((uint2*)(A + (size_t)w * 64) + fl) = pk;
  }
}

// ---------------- MFMA dual GEMM v3 (both directions, one dispatch) ----------------
// Block = 4 waves x 64 rows = 256 rows. Weights staged ONCE per block:
// coalesced linear uint4 global reads (4/thread), LDS-written pre-permuted
// so frag f = wlds[f*64 + lane] -> lane-contiguous conflict-free
// ds_read_b128 frag loads. All 16 frags in registers across 4 subtiles.
// Next-subtile A/X prefetched under current MFMAs. C staged through
// per-wave LDS f32 tile -> coalesced dwordx4 Y stores (R11-proven).
// Last layer: pooled reduction, no Y write.

__global__ __launch_bounds__(256) void fgemm3_kernel(
    const unsigned short* __restrict__ A1, const unsigned short* __restrict__ X1,
    const unsigned short* __restrict__ Wl1, const unsigned short* __restrict__ Wr1,
    const float* __restrict__ bias1, unsigned short* __restrict__ Y1, int N1,
    const unsigned short* __restrict__ A2, const unsigned short* __restrict__ X2,
    const unsigned short* __restrict__ Wl2, const unsigned short* __restrict__ Wr2,
    const float* __restrict__ bias2, unsigned short* __restrict__ Y2, int N2,
    int g1, float* __restrict__ pooled, int lastLayer) {
  __shared__ __align__(16) uint4 wlds[1024];      // 16KB: frag f at [f*64+lane]
  __shared__ __align__(16) float cst[4][16][68];  // 17.4KB: per-wave C transpose
  __shared__ float pacc[64];
  int bid = blockIdx.x;
  const unsigned short *A, *X, *Wlb, *Wrb;
  const float* bias;
  unsigned short* Y;
  int N;
  if (bid < g1) {
    A = A1; X = X1; Wlb = Wl1; Wrb = Wr1; bias = bias1; Y = Y1; N = N1;
  } else {
    bid -= g1;
    A = A2; X = X2; Wlb = Wl2; Wrb = Wr2; bias = bias2; Y = Y2; N = N2;
  }
  int t = threadIdx.x;
  if (lastLayer && t < 64) pacc[t] = 0.f;

  // ---- coalesced weight staging with frag permutation ----
  // chunk c (16B) of Wl||Wr: op=c>>9, row=(c&511)>>3, ch8=c&7
  // -> frag f = op*8 + (ch8>>2)*4 + (row>>4), lane = (ch8&3)*16 + (row&15)
#pragma unroll
  for (int p = 0; p < 4; ++p) {
    int c = p * 256 + t;
    int op = c >> 9;
    int c9 = c & 511;
    int row = c9 >> 3;
    int ch8 = c9 & 7;
    const unsigned short* W = op ? Wrb : Wlb;
    uint4 v = *(const uint4*)(W + row * 64 + ch8 * 8);
    int f = op * 8 + (ch8 >> 2) * 4 + (row >> 4);
    wlds[f * 64 + (ch8 & 3) * 16 + (row & 15)] = v;
  }

  int wid = t >> 6, lane = t & 63;
  int lr = lane & 15;  // row within A/B frags; col (=h low) within C
  int kg = lane >> 4;  // k-subgroup 0..3
  int w0 = bid * 256 + wid * 64;  // this wave's first row

  float bias_r[4];
#pragma unroll
  for (int nt = 0; nt < 4; ++nt) bias_r[nt] = bias[nt * 16 + lr];

  __syncthreads();  // weights visible

  union UB { uint4 u; bh8 v; };
  // all 16 weight fragments -> registers, reused by all 4 subtiles
  UB bl0[4], bl1[4], br0[4], br1[4];
#pragma unroll
  for (int nt = 0; nt < 4; ++nt) {
    bl0[nt].u = wlds[(0 + nt) * 64 + lane];   // Wl, k 0..31
    bl1[nt].u = wlds[(4 + nt) * 64 + lane];   // Wl, k 32..63
    br0[nt].u = wlds[(8 + nt) * 64 + lane];   // Wr, k 0..31
    br1[nt].u = wlds[(12 + nt) * 64 + lane];  // Wr, k 32..63
  }

  // prefetch subtile 0
  int mr = min(w0 + lr, N - 1);
  const bh8* ar = (const bh8*)(A + (size_t)mr * 64);
  const bh8* xr = (const bh8*)(X + (size_t)mr * 64);
  bh8 a0 = ar[kg], a1 = ar[4 + kg], x0 = xr[kg], x1 = xr[4 + kg];

  float psum[4] = {0.f, 0.f, 0.f, 0.f};

#pragma unroll
  for (int sub = 0; sub < 4; ++sub) {
    bh8 na0 = a0, na1 = a1, nx0 = x0, nx1 = x1;
    if (sub < 3) {  // prefetch next subtile under this one's MFMAs
      int mrn = min(w0 + (sub + 1) * 16 + lr, N - 1);
      const bh8* arn = (const bh8*)(A + (size_t)mrn * 64);
      const bh8* xrn = (const bh8*)(X + (size_t)mrn * 64);
      na0 = arn[kg]; na1 = arn[4 + kg]; nx0 = xrn[kg]; nx1 = xrn[4 + kg];
    }
    fx4 acc[4];
#pragma unroll
    for (int nt = 0; nt < 4; ++nt) acc[nt] = (fx4){0.f, 0.f, 0.f, 0.f};
#pragma unroll
    for (int nt = 0; nt < 4; ++nt)
      acc[nt] = __builtin_amdgcn_mfma_f32_16x16x32_bf16(a0, bl0[nt].v, acc[nt], 0, 0, 0);
#pragma unroll
    for (int nt = 0; nt < 4; ++nt)
      acc[nt] = __builtin_amdgcn_mfma_f32_16x16x32_bf16(a1, bl1[nt].v, acc[nt], 0, 0, 0);
#pragma unroll
    for (int nt = 0; nt < 4; ++nt)
      acc[nt] = __builtin_amdgcn_mfma_f32_16x16x32_bf16(x0, br0[nt].v, acc[nt], 0, 0, 0);
#pragma unroll
    for (int nt = 0; nt < 4; ++nt)
      acc[nt] = __builtin_amdgcn_mfma_f32_16x16x32_bf16(x1, br1[nt].v, acc[nt], 0, 0, 0);

    int mbase = w0 + sub * 16;
    if (!lastLayer) {
      // stage C (bias added) into per-wave tile: row = kg*4+j, col = h
#pragma unroll
      for (int nt = 0; nt < 4; ++nt)
#pragma unroll
        for (int j = 0; j < 4; ++j)
          cst[wid][kg * 4 + j][nt * 16 + lr] = acc[nt][j] + bias_r[nt];
      // per-wave tile readback (R11-proven; same wave, no barrier needed)
#pragma unroll
      for (int s = 0; s < 2; ++s) {
        int idx = lane + 64 * s;  // 16 rows x 8 chunks of 8 h
        int r = idx >> 3, c = idx & 7;
        float4 v0 = *(const float4*)&cst[wid][r][c * 8];
        float4 v1 = *(const float4*)&cst[wid][r][c * 8 + 4];
        uint4 pk;
        pk.x = (unsigned int)f2bf(v0.x) | ((unsigned int)f2bf(v0.y) << 16);
        pk.y = (unsigned int)f2bf(v0.z) | ((unsigned int)f2bf(v0.w) << 16);
        pk.z = (unsigned int)f2bf(v1.x) | ((unsigned int)f2bf(v1.y) << 16);
        pk.w = (unsigned int)f2bf(v1.z) | ((unsigned int)f2bf(v1.w) << 16);
        int m = mbase + r;
        if (m < N) ((uint4*)(Y + (size_t)m * 64))[c] = pk;
      }
    } else {
      // pooled-only epilogue: no Y write
#pragma unroll
      for (int nt = 0; nt < 4; ++nt) {
#pragma unroll
        for (int j = 0; j < 4; ++j) {
          int m = mbase + kg * 4 + j;
          if (m < N) psum[nt] += acc[nt][j] + bias_r[nt];
        }
      }
    }
    a0 = na0; a1 = na1; x0 = nx0; x1 = nx1;
  }

  if (lastLayer) {
#pragma unroll
    for (int nt = 0; nt < 4; ++nt) atomicAdd(&pacc[nt * 16 + lr], psum[nt]);
    __syncthreads();
    if (t < 64) atomicAdd(&pooled[t], pacc[t]);
  }
}

// ---------------- final linear ----------------

__global__ void final_kernel(const float* __restrict__ pooled, const float* __restrict__ linW,
                             const float* __restrict__ linb, float* __restrict__ out, float invM) {
  int t = threadIdx.x;  // 64 threads
  float v = pooled[t] * invM * linW[t];
#pragma unroll
  for (int o = 32; o > 0; o >>= 1) v += __shfl_down(v, o, 64);
  if (t == 0) out[0] = v + linb[0];
}

// ---------------- launch ----------------

extern "C" void kernel_launch(void* const* d_in, const int* in_sizes, int n_in,
                              void* d_out, int out_size, void* d_ws, size_t ws_size,
                              hipStream_t stream) {
  const float* x_source = (const float*)d_in[0];
  const float* x_target = (const float*)d_in[1];
  float* scratchA = (float*)d_in[2];  // edge_attr_s2t: 12.8M floats, unused input
  float* scratchB = (float*)d_in[3];  // edge_attr_t2s: 12.8M floats, unused input
  const float* W_l_s2t = (const float*)d_in[4];
  const float* b_s2t   = (const float*)d_in[5];
  const float* W_r_s2t = (const float*)d_in[6];
  const float* W_l_t2s = (const float*)d_in[7];
  const float* b_t2s   = (const float*)d_in[8];
  const float* W_r_t2s = (const float*)d_in[9];
  const float* lin_W   = (const float*)d_in[10];
  const float* lin_b   = (const float*)d_in[11];
  const int* ei_s2t    = (const int*)d_in[12];
  const int* ei_t2s    = (const int*)d_in[13];

  const int NS = in_sizes[0] / FDIM;
  const int NT = in_sizes[1] / FDIM;
  const int E  = in_sizes[12] / 2;
  const int L  = in_sizes[4] / (FDIM * FDIM);
  const size_t NF = (size_t)NS * FDIM;        // 6.4M elems
  const size_t WN = (size_t)L * FDIM * FDIM;  // per weight array, elems

  // scratchA: S0, T0 (bf16 NF), Wb x4, csr_t, csr_s, inv_t, inv_s, off_t, off_s
  unsigned short* S0 = (unsigned short*)scratchA;          // NF bf16
  unsigned short* T0 = S0 + NF;                            // NF bf16
  unsigned short* WbLs2t = T0 + NF;                        // L*4096 bf16
  unsigned short* WbRs2t = WbLs2t + WN;
  unsigned short* WbLt2s = WbRs2t + WN;
  unsigned short* WbRt2s = WbLt2s + WN;
  int*   csr_t  = (int*)(WbRt2s + WN);        // E
  int*   csr_s  = csr_t + E;                  // E
  float* inv_t  = (float*)(csr_s + E);        // NS
  float* inv_s  = inv_t + NS;                 // NS
  int*   off_t  = (int*)(inv_s + NS);         // NS+1
  int*   off_s  = off_t + NS + 1;             // NS+1

  const int NB_T = (NT + 255) >> 8;
  const int NB_S = (NS + 255) >> 8;
  const int B    = (E + 4095) >> 12;

  // scratchB: S1, T1, binned_t, binned_s, H_t, H_s, tot/boff x2
  unsigned short* S1 = (unsigned short*)scratchB;          // NF bf16
  unsigned short* T1 = S1 + NF;                            // NF bf16
  int* binned_t = (int*)(T1 + NF);                         // E
  int* binned_s = binned_t + E;                            // E
  int* H_t      = binned_s + E;                            // B*NB_T
  int* H_s      = H_t + (size_t)B * NB_T;                  // B*NB_S
  int* tot_t    = H_s + (size_t)B * NB_S;                  // 512
  int* boff_t   = tot_t + 512;                             // 512
  int* tot_s    = boff_t + 512;                            // 512
  int* boff_s   = tot_s + 512;                             // 512
  // A_s aliases binned_t+binned_s (dead after build; 2*E*4 == NF*2 bytes)
  unsigned short* As = (unsigned short*)binned_t;

  // d_ws: A_t (bf16 NF) + pooled
  unsigned short* At = (unsigned short*)d_ws;
  float* pooled = (float*)(At + NF);

  const int* src_s2t = ei_s2t;
  const int* dst_s2t = ei_s2t + E;
  const int* src_t2s = ei_t2s;
  const int* dst_t2s = ei_t2s + E;

  // --- CSR build, both directions per pass ---
  hist2_kernel<<<2 * B, 256, 0, stream>>>(dst_s2t, H_t, NB_T, dst_t2s, H_s, NB_S, E, B);
  colscan2_kernel<<<NB_T + NB_S, 256, 0, stream>>>(H_t, tot_t, NB_T, H_s, tot_s, NB_S, B);
  totscan2_kernel<<<2, 256, 0, stream>>>(tot_t, boff_t, NB_T, tot_s, boff_s, NB_S);
  bin2_kernel<<<2 * B, 256, 0, stream>>>(src_s2t, dst_s2t, H_t, boff_t, binned_t, NB_T,
                                         src_t2s, dst_t2s, H_s, boff_s, binned_s, NB_S, E, B);
  build2_kernel<<<NB_T + NB_S, 256, 0, stream>>>(binned_t, boff_t, off_t, csr_t, inv_t, NT, NB_T,
                                                 binned_s, boff_s, off_s, csr_s, inv_s, NS, NB_S, E);

  // --- bf16 packs: features (2 dispatches) + all weights (1 dispatch) ---
  int gP = (int)((NF / 4 + 255) / 256);
  pack_kernel<<<gP, 256, 0, stream>>>(x_source, S0, (int)(NF / 4));
  pack_kernel<<<gP, 256, 0, stream>>>(x_target, T0, (int)(NF / 4));
  int n4W = (int)(WN / 4);
  int gW = (n4W + 255) / 256;
  pack4_kernel<<<4 * gW, 256, 0, stream>>>(W_l_s2t, WbLs2t, W_r_s2t, WbRs2t,
                                           W_l_t2s, WbLt2s, W_r_t2s, WbRt2s, n4W, gW);

  hipMemsetAsync(pooled, 0, 64 * 4, stream);

  unsigned short* xs_in = S0;
  unsigned short* xt_in = T0;
  unsigned short* xs_out = S1;
  unsigned short* xt_out = T1;

  int aT = (NT * 64 + 255) / 256;  // agg blocks (4 nodes/block)
  int aS = (NS * 64 + 255) / 256;
  int gT3 = (NT + 255) / 256;      // fgemm3 blocks (256 rows/block)
  int gS3 = (NS + 255) / 256;

  for (int l = 0; l < L; ++l) {
    const unsigned short* Wl1 = WbLs2t + (size_t)l * 4096;
    const unsigned short* Wr1 = WbRs2t + (size_t)l * 4096;
    const float* bb1 = b_s2t + (size_t)l * 64;
    const unsigned short* Wl2 = WbLt2s + (size_t)l * 4096;
    const unsigned short* Wr2 = WbRt2s + (size_t)l * 4096;
    const float* bb2 = b_t2s + (size_t)l * 64;
    int last = (l == L - 1) ? 1 : 0;

    // A_t = mean_agg(xs_in) over s2t CSR; A_s = mean_agg(xt_in) over t2s CSR
    agg2_kernel<<<aT + aS, 256, 0, stream>>>(xs_in, off_t, csr_t, inv_t, At, NT, aT,
                                             xt_in, off_s, csr_s, inv_s, As, NS);
    // xt_out = A_t@Wl1^T + xt_in@Wr1^T + b1 ; xs_out = A_s@Wl2^T + xs_in@Wr2^T + b2
    fgemm3_kernel<<<gT3 + gS3, 256, 0, stream>>>(At, xt_in, Wl1, Wr1, bb1, xt_out, NT,
                                                 As, xs_in, Wl2, Wr2, bb2, xs_out, NS,
                                                 gT3, pooled, last);

    unsigned short* ts = xs_in; xs_in = xs_out; xs_out = ts;
    unsigned short* tt = xt_in; xt_in = xt_out; xt_out = tt;
  }

  final_kernel<<<1, 64, 0, stream>>>(pooled, lin_W, lin_b, (float*)d_out,
                                     1.0f / (float)(NS + NT));
}

// Round 7
// 514.620 us; speedup vs baseline: 1.3669x; 1.2004x over previous
//
#include <hip/hip_runtime.h>

// BipartiteGNN: 3-layer bipartite SAGEConv + global mean pool + linear.
// NS=NT=100000, E=1.6M per direction, F=H=64.
//
// R14: R13 won (618 µs; fgemm3 fix confirmed, out of top-5). Top-5 now all
// agg2 (3 x 97.5 = 293 µs). agg2's VGPR_Count=12 proves the gather is
// ILP-starved: one load in flight per lane, serial addr->load->wait->unpack.
// agg3 restructures: GROUP-PER-NODE — each 16-lane group owns its own dst
// node (4 nodes/wave):
//  - no cross-group reduce (saves 12 shfl+add per node), no idle lanes;
//  - width-16 __shfl broadcasts; ALL control flow group-uniform (every
//    lane of a group computes the same node -> same trip counts), shfl
//    sources never leave the group -> R7 active-lane discipline holds at
//    group scope even when sibling groups exit;
//  - unroll x2: two row loads issued back-to-back -> 2x MLP (8 rows in
//    flight per wave vs 4).
// Everything else byte-identical to R13 (fgemm3, CSR build, packs, final).

#define FDIM 64

typedef short bh8 __attribute__((ext_vector_type(8)));  // 8 bf16 = 4 VGPR
typedef float fx4 __attribute__((ext_vector_type(4)));  // MFMA accumulator

__device__ __forceinline__ unsigned short f2bf(float f) {
  unsigned int u = __float_as_uint(f);
  unsigned int r = u + 0x7FFFu + ((u >> 16) & 1u);  // round-to-nearest-even
  return (unsigned short)(r >> 16);
}
__device__ __forceinline__ float bf2f(unsigned short h) {
  return __uint_as_float((unsigned int)h << 16);
}

// ---------------- CSR build (bucketed, atomic-free at global scope) ----------------
// Each pass handles BOTH directions in one dispatch (blockIdx selects).

__global__ __launch_bounds__(256) void hist2_kernel(const int* __restrict__ dstT,
                                                    int* __restrict__ HT, int NBT,
                                                    const int* __restrict__ dstS,
                                                    int* __restrict__ HS, int NBS,
                                                    int E, int B) {
  __shared__ int lh[512];
  int b = blockIdx.x;
  const int* dst;
  int* H;
  int NB;
  if (b < B) {
    dst = dstT; H = HT; NB = NBT;
  } else {
    b -= B; dst = dstS; H = HS; NB = NBS;
  }
  int t = threadIdx.x;
  lh[t] = 0;
  lh[t + 256] = 0;
  __syncthreads();
  int base = b * 4096;
#pragma unroll
  for (int i = 0; i < 16; ++i) {
    int e = base + i * 256 + t;
    if (e < E) atomicAdd(&lh[dst[e] >> 8], 1);
  }
  __syncthreads();
  int* row = H + (size_t)b * NB;
  if (t < NB) row[t] = lh[t];
  if (t + 256 < NB) row[t + 256] = lh[t + 256];
}

__global__ __launch_bounds__(256) void colscan2_kernel(int* __restrict__ HT,
                                                       int* __restrict__ totT, int NBT,
                                                       int* __restrict__ HS,
                                                       int* __restrict__ totS, int NBS,
                                                       int B) {
  __shared__ int sh[512];
  int k = blockIdx.x;
  int* H;
  int* tot;
  int NB;
  if (k < NBT) {
    H = HT; tot = totT; NB = NBT;
  } else {
    k -= NBT; H = HS; tot = totS; NB = NBS;
  }
  int t = threadIdx.x;
  int v0 = (t < B) ? H[(size_t)t * NB + k] : 0;
  int v1 = (t + 256 < B) ? H[(size_t)(t + 256) * NB + k] : 0;
  sh[t] = v0;
  sh[t + 256] = v1;
  __syncthreads();
  for (int d = 1; d < 512; d <<= 1) {
    int a0 = (t >= d) ? sh[t - d] : 0;
    int a1 = (t + 256 >= d) ? sh[t + 256 - d] : 0;
    __syncthreads();
    sh[t] += a0;
    sh[t + 256] += a1;
    __syncthreads();
  }
  if (t < B) H[(size_t)t * NB + k] = sh[t] - v0;  // exclusive
  if (t + 256 < B) H[(size_t)(t + 256) * NB + k] = sh[t + 256] - v1;
  if (t == 0) tot[k] = sh[511];
}

__global__ __launch_bounds__(256) void totscan2_kernel(const int* __restrict__ totT,
                                                       int* __restrict__ boffT, int NBT,
                                                       const int* __restrict__ totS,
                                                       int* __restrict__ boffS, int NBS) {
  __shared__ int sh[512];
  const int* tot = (blockIdx.x == 0) ? totT : totS;
  int* boff = (blockIdx.x == 0) ? boffT : boffS;
  int NB = (blockIdx.x == 0) ? NBT : NBS;
  int t = threadIdx.x;
  sh[t] = (t < NB) ? tot[t] : 0;
  sh[t + 256] = (t + 256 < NB) ? tot[t + 256] : 0;
  __syncthreads();
  for (int d = 1; d < 512; d <<= 1) {
    int a0 = (t >= d) ? sh[t - d] : 0;
    int a1 = (t + 256 >= d) ? sh[t + 256 - d] : 0;
    __syncthreads();
    sh[t] += a0;
    sh[t + 256] += a1;
    __syncthreads();
  }
  if (t < NB) boff[t] = (t > 0) ? sh[t - 1] : 0;
  if (t + 256 < NB) boff[t + 256] = sh[t + 255];
}

__global__ __launch_bounds__(256) void bin2_kernel(const int* __restrict__ srcT,
                                                   const int* __restrict__ dstT,
                                                   const int* __restrict__ HT,
                                                   const int* __restrict__ boffT,
                                                   int* __restrict__ binnedT, int NBT,
                                                   const int* __restrict__ srcS,
                                                   const int* __restrict__ dstS,
                                                   const int* __restrict__ HS,
                                                   const int* __restrict__ boffS,
                                                   int* __restrict__ binnedS, int NBS,
                                                   int E, int B) {
  __shared__ int cur[512];
  int b = blockIdx.x;
  const int *src, *dst, *H, *boff;
  int* binned;
  int NB;
  if (b < B) {
    src = srcT; dst = dstT; H = HT; boff = boffT; binned = binnedT; NB = NBT;
  } else {
    b -= B; src = srcS; dst = dstS; H = HS; boff = boffS; binned = binnedS; NB = NBS;
  }
  int t = threadIdx.x;
  const int* row = H + (size_t)b * NB;
  if (t < NB) cur[t] = row[t] + boff[t];
  if (t + 256 < NB) cur[t + 256] = row[t + 256] + boff[t + 256];
  __syncthreads();
  int base = b * 4096;
#pragma unroll
  for (int i = 0; i < 16; ++i) {
    int e = base + i * 256 + t;
    if (e < E) {
      int d = dst[e];
      int p = atomicAdd(&cur[d >> 8], 1);  // LDS atomic
      binned[p] = (src[e] << 8) | (d & 255);
    }
  }
}

__global__ __launch_bounds__(256) void build2_kernel(const int* __restrict__ binnedT,
                                                     const int* __restrict__ boffT,
                                                     int* __restrict__ offT,
                                                     int* __restrict__ csrT,
                                                     float* __restrict__ invT,
                                                     int NT, int NBT,
                                                     const int* __restrict__ binnedS,
                                                     const int* __restrict__ boffS,
                                                     int* __restrict__ offS,
                                                     int* __restrict__ csrS,
                                                     float* __restrict__ invS,
                                                     int NS, int NBS, int E) {
  __shared__ int cnt[256];
  __shared__ int lofs[256];
  __shared__ int cur[256];
  int b = blockIdx.x;
  const int *binned, *boff;
  int *off, *csr;
  float* inv_deg;
  int N, NB;
  if (b < NBT) {
    binned = binnedT; boff = boffT; off = offT; csr = csrT; inv_deg = invT;
    N = NT; NB = NBT;
  } else {
    b -= NBT;
    binned = binnedS; boff = boffS; off = offS; csr = csrS; inv_deg = invS;
    N = NS; NB = NBS;
  }
  int t = threadIdx.x;
  int n0 = b << 8;
  cnt[t] = 0;
  __syncthreads();
  int s0 = boff[b];
  int s1 = (b + 1 < NB) ? boff[b + 1] : E;
  for (int i = s0 + t; i < s1; i += 256) {
    atomicAdd(&cnt[binned[i] & 255], 1);  // LDS atomic
  }
  __syncthreads();
  int c = cnt[t];
  lofs[t] = c;
  __syncthreads();
  for (int d = 1; d < 256; d <<= 1) {
    int v = (t >= d) ? lofs[t - d] : 0;
    __syncthreads();
    lofs[t] += v;
    __syncthreads();
  }
  int excl = lofs[t] - c;
  cur[t] = s0 + excl;
  int node = n0 + t;
  if (node < N) {
    off[node] = s0 + excl;
    inv_deg[node] = 1.0f / (float)max(c, 1);
    if (node == N - 1) off[N] = s0 + excl + c;
  }
  __syncthreads();
  for (int i = s0 + t; i < s1; i += 256) {
    int e = binned[i];
    int r = atomicAdd(&cur[e & 255], 1);  // LDS atomic
    csr[r] = e >> 8;
  }
}

// ---------------- fp32 -> bf16 pack ----------------

__global__ void pack_kernel(const float* __restrict__ X, unsigned short* __restrict__ Y, int n4) {
  int i = blockIdx.x * 256 + threadIdx.x;
  if (i < n4) {
    float4 v = ((const float4*)X)[i];
    uint2 pk;
    pk.x = (unsigned int)f2bf(v.x) | ((unsigned int)f2bf(v.y) << 16);
    pk.y = (unsigned int)f2bf(v.z) | ((unsigned int)f2bf(v.w) << 16);
    ((uint2*)Y)[i] = pk;
  }
}

__global__ void pack4_kernel(const float* __restrict__ X0, unsigned short* __restrict__ Y0,
                             const float* __restrict__ X1, unsigned short* __restrict__ Y1,
                             const float* __restrict__ X2, unsigned short* __restrict__ Y2,
                             const float* __restrict__ X3, unsigned short* __restrict__ Y3,
                             int n4, int gPer) {
  int seg = blockIdx.x / gPer;
  int i = (blockIdx.x - seg * gPer) * 256 + threadIdx.x;
  const float* X = (seg == 0) ? X0 : (seg == 1) ? X1 : (seg == 2) ? X2 : X3;
  unsigned short* Y = (seg == 0) ? Y0 : (seg == 1) ? Y1 : (seg == 2) ? Y2 : Y3;
  if (i < n4) {
    float4 v = ((const float4*)X)[i];
    uint2 pk;
    pk.x = (unsigned int)f2bf(v.x) | ((unsigned int)f2bf(v.y) << 16);
    pk.y = (unsigned int)f2bf(v.z) | ((unsigned int)f2bf(v.w) << 16);
    ((uint2*)Y)[i] = pk;
  }
}

// ---------------- aggregation v3: group-per-node (both directions, one dispatch) ----------------
// 16 groups of 16 lanes per block; each group owns ONE dst node (16/block).
// Group lane fl covers features [fl*4, fl*4+4) via uint2 loads. Row index
// broadcast with width-16 shfl; all control flow is group-uniform (all 16
// lanes share the node), so every shfl source lane is active within its
// group even when sibling groups have exited. Unroll x2 for MLP.

__global__ __launch_bounds__(256) void agg3_kernel(
    const unsigned short* __restrict__ MsgT, const int* __restrict__ offT,
    const int* __restrict__ csrT, const float* __restrict__ invT,
    unsigned short* __restrict__ AT, int NT, int gT,
    const unsigned short* __restrict__ MsgS, const int* __restrict__ offS,
    const int* __restrict__ csrS, const float* __restrict__ invS,
    unsigned short* __restrict__ AS, int NS) {
  int b = blockIdx.x;
  const unsigned short* Msg;
  const int *off, *csr;
  const float* inv_deg;
  unsigned short* A;
  int N;
  if (b < gT) {
    Msg = MsgT; off = offT; csr = csrT; inv_deg = invT; A = AT; N = NT;
  } else {
    b -= gT;
    Msg = MsgS; off = offS; csr = csrS; inv_deg = invS; A = AS; N = NS;
  }
  int t = threadIdx.x;
  int fl = t & 15;                 // feature sublane within group
  int node = b * 16 + (t >> 4);    // group's dst node
  if (node >= N) return;           // group-uniform
  int s0 = off[node], s1 = off[node + 1];
  float ax = 0.f, ay = 0.f, az = 0.f, aw = 0.f;
  for (int c = s0; c < s1; c += 16) {
    int idx = c + fl;
    int mysrc = (idx < s1) ? csr[idx] : 0;
    int rem = min(16, s1 - c);     // group-uniform
    int jm = rem & ~1;
    for (int j = 0; j < jm; j += 2) {
      int sa = __shfl(mysrc, j, 16);      // within-group broadcast
      int sb = __shfl(mysrc, j + 1, 16);
      uint2 va = *((const uint2*)(Msg + (size_t)sa * 64) + fl);
      uint2 vb = *((const uint2*)(Msg + (size_t)sb * 64) + fl);
      ax += bf2f((unsigned short)(va.x & 0xffffu));
      ay += bf2f((unsigned short)(va.x >> 16));
      az += bf2f((unsigned short)(va.y & 0xffffu));
      aw += bf2f((unsigned short)(va.y >> 16));
      ax += bf2f((unsigned short)(vb.x & 0xffffu));
      ay += bf2f((unsigned short)(vb.x >> 16));
      az += bf2f((unsigned short)(vb.y & 0xffffu));
      aw += bf2f((unsigned short)(vb.y >> 16));
    }
    if (rem & 1) {                 // group-uniform tail
      int s = __shfl(mysrc, jm, 16);
      uint2 v = *((const uint2*)(Msg + (size_t)s * 64) + fl);
      ax += bf2f((unsigned short)(v.x & 0xffffu));
      ay += bf2f((unsigned short)(v.x >> 16));
      az += bf2f((unsigned short)(v.y & 0xffffu));
      aw += bf2f((unsigned short)(v.y >> 16));
    }
  }
  float id = inv_deg[node];
  uint2 pk;
  pk.x = (unsigned int)f2bf(ax * id) | ((unsigned int)f2bf(ay * id) << 16);
  pk.y = (unsigned int)f2bf(az * id) | ((unsigned int)f2bf(aw * id) << 16);
  *((uint2*)(A + (size_t)node * 64) + fl) = pk;
}

// ---------------- MFMA dual GEMM v3 (both directions, one dispatch) ----------------
// R13-proven: block = 4 waves x 64 rows = 256 rows; weights staged once per
// block with coalesced linear uint4 reads, LDS pre-permuted so frag f =
// wlds[f*64+lane] (lane-contiguous conflict-free ds_read_b128); 16 frags in
// registers across 4 subtiles; next-subtile A/X prefetch; C staged through
// per-wave LDS f32 tile -> coalesced dwordx4 stores; pooled epilogue last.

__global__ __launch_bounds__(256) void fgemm3_kernel(
    const unsigned short* __restrict__ A1, const unsigned short* __restrict__ X1,
    const unsigned short* __restrict__ Wl1, const unsigned short* __restrict__ Wr1,
    const float* __restrict__ bias1, unsigned short* __restrict__ Y1, int N1,
    const unsigned short* __restrict__ A2, const unsigned short* __restrict__ X2,
    const unsigned short* __restrict__ Wl2, const unsigned short* __restrict__ Wr2,
    const float* __restrict__ bias2, unsigned short* __restrict__ Y2, int N2,
    int g1, float* __restrict__ pooled, int lastLayer) {
  __shared__ __align__(16) uint4 wlds[1024];      // 16KB: frag f at [f*64+lane]
  __shared__ __align__(16) float cst[4][16][68];  // 17.4KB: per-wave C transpose
  __shared__ float pacc[64];
  int bid = blockIdx.x;
  const unsigned short *A, *X, *Wlb, *Wrb;
  const float* bias;
  unsigned short* Y;
  int N;
  if (bid < g1) {
    A = A1; X = X1; Wlb = Wl1; Wrb = Wr1; bias = bias1; Y = Y1; N = N1;
  } else {
    bid -= g1;
    A = A2; X = X2; Wlb = Wl2; Wrb = Wr2; bias = bias2; Y = Y2; N = N2;
  }
  int t = threadIdx.x;
  if (lastLayer && t < 64) pacc[t] = 0.f;

  // ---- coalesced weight staging with frag permutation ----
  // chunk c (16B) of Wl||Wr: op=c>>9, row=(c&511)>>3, ch8=c&7
  // -> frag f = op*8 + (ch8>>2)*4 + (row>>4), lane = (ch8&3)*16 + (row&15)
#pragma unroll
  for (int p = 0; p < 4; ++p) {
    int c = p * 256 + t;
    int op = c >> 9;
    int c9 = c & 511;
    int row = c9 >> 3;
    int ch8 = c9 & 7;
    const unsigned short* W = op ? Wrb : Wlb;
    uint4 v = *(const uint4*)(W + row * 64 + ch8 * 8);
    int f = op * 8 + (ch8 >> 2) * 4 + (row >> 4);
    wlds[f * 64 + (ch8 & 3) * 16 + (row & 15)] = v;
  }

  int wid = t >> 6, lane = t & 63;
  int lr = lane & 15;  // row within A/B frags; col (=h low) within C
  int kg = lane >> 4;  // k-subgroup 0..3
  int w0 = bid * 256 + wid * 64;  // this wave's first row

  float bias_r[4];
#pragma unroll
  for (int nt = 0; nt < 4; ++nt) bias_r[nt] = bias[nt * 16 + lr];

  __syncthreads();  // weights visible

  union UB { uint4 u; bh8 v; };
  // all 16 weight fragments -> registers, reused by all 4 subtiles
  UB bl0[4], bl1[4], br0[4], br1[4];
#pragma unroll
  for (int nt = 0; nt < 4; ++nt) {
    bl0[nt].u = wlds[(0 + nt) * 64 + lane];   // Wl, k 0..31
    bl1[nt].u = wlds[(4 + nt) * 64 + lane];   // Wl, k 32..63
    br0[nt].u = wlds[(8 + nt) * 64 + lane];   // Wr, k 0..31
    br1[nt].u = wlds[(12 + nt) * 64 + lane];  // Wr, k 32..63
  }

  // prefetch subtile 0
  int mr = min(w0 + lr, N - 1);
  const bh8* ar = (const bh8*)(A + (size_t)mr * 64);
  const bh8* xr = (const bh8*)(X + (size_t)mr * 64);
  bh8 a0 = ar[kg], a1 = ar[4 + kg], x0 = xr[kg], x1 = xr[4 + kg];

  float psum[4] = {0.f, 0.f, 0.f, 0.f};

#pragma unroll
  for (int sub = 0; sub < 4; ++sub) {
    bh8 na0 = a0, na1 = a1, nx0 = x0, nx1 = x1;
    if (sub < 3) {  // prefetch next subtile under this one's MFMAs
      int mrn = min(w0 + (sub + 1) * 16 + lr, N - 1);
      const bh8* arn = (const bh8*)(A + (size_t)mrn * 64);
      const bh8* xrn = (const bh8*)(X + (size_t)mrn * 64);
      na0 = arn[kg]; na1 = arn[4 + kg]; nx0 = xrn[kg]; nx1 = xrn[4 + kg];
    }
    fx4 acc[4];
#pragma unroll
    for (int nt = 0; nt < 4; ++nt) acc[nt] = (fx4){0.f, 0.f, 0.f, 0.f};
#pragma unroll
    for (int nt = 0; nt < 4; ++nt)
      acc[nt] = __builtin_amdgcn_mfma_f32_16x16x32_bf16(a0, bl0[nt].v, acc[nt], 0, 0, 0);
#pragma unroll
    for (int nt = 0; nt < 4; ++nt)
      acc[nt] = __builtin_amdgcn_mfma_f32_16x16x32_bf16(a1, bl1[nt].v, acc[nt], 0, 0, 0);
#pragma unroll
    for (int nt = 0; nt < 4; ++nt)
      acc[nt] = __builtin_amdgcn_mfma_f32_16x16x32_bf16(x0, br0[nt].v, acc[nt], 0, 0, 0);
#pragma unroll
    for (int nt = 0; nt < 4; ++nt)
      acc[nt] = __builtin_amdgcn_mfma_f32_16x16x32_bf16(x1, br1[nt].v, acc[nt], 0, 0, 0);

    int mbase = w0 + sub * 16;
    if (!lastLayer) {
      // stage C (bias added) into per-wave tile: row = kg*4+j, col = h
#pragma unroll
      for (int nt = 0; nt < 4; ++nt)
#pragma unroll
        for (int j = 0; j < 4; ++j)
          cst[wid][kg * 4 + j][nt * 16 + lr] = acc[nt][j] + bias_r[nt];
      // per-wave tile readback (R11-proven; same wave, no barrier needed)
#pragma unroll
      for (int s = 0; s < 2; ++s) {
        int idx = lane + 64 * s;  // 16 rows x 8 chunks of 8 h
        int r = idx >> 3, c = idx & 7;
        float4 v0 = *(const float4*)&cst[wid][r][c * 8];
        float4 v1 = *(const float4*)&cst[wid][r][c * 8 + 4];
        uint4 pk;
        pk.x = (unsigned int)f2bf(v0.x) | ((unsigned int)f2bf(v0.y) << 16);
        pk.y = (unsigned int)f2bf(v0.z) | ((unsigned int)f2bf(v0.w) << 16);
        pk.z = (unsigned int)f2bf(v1.x) | ((unsigned int)f2bf(v1.y) << 16);
        pk.w = (unsigned int)f2bf(v1.z) | ((unsigned int)f2bf(v1.w) << 16);
        int m = mbase + r;
        if (m < N) ((uint4*)(Y + (size_t)m * 64))[c] = pk;
      }
    } else {
      // pooled-only epilogue: no Y write
#pragma unroll
      for (int nt = 0; nt < 4; ++nt) {
#pragma unroll
        for (int j = 0; j < 4; ++j) {
          int m = mbase + kg * 4 + j;
          if (m < N) psum[nt] += acc[nt][j] + bias_r[nt];
        }
      }
    }
    a0 = na0; a1 = na1; x0 = nx0; x1 = nx1;
  }

  if (lastLayer) {
#pragma unroll
    for (int nt = 0; nt < 4; ++nt) atomicAdd(&pacc[nt * 16 + lr], psum[nt]);
    __syncthreads();
    if (t < 64) atomicAdd(&pooled[t], pacc[t]);
  }
}

// ---------------- final linear ----------------

__global__ void final_kernel(const float* __restrict__ pooled, const float* __restrict__ linW,
                             const float* __restrict__ linb, float* __restrict__ out, float invM) {
  int t = threadIdx.x;  // 64 threads
  float v = pooled[t] * invM * linW[t];
#pragma unroll
  for (int o = 32; o > 0; o >>= 1) v += __shfl_down(v, o, 64);
  if (t == 0) out[0] = v + linb[0];
}

// ---------------- launch ----------------

extern "C" void kernel_launch(void* const* d_in, const int* in_sizes, int n_in,
                              void* d_out, int out_size, void* d_ws, size_t ws_size,
                              hipStream_t stream) {
  const float* x_source = (const float*)d_in[0];
  const float* x_target = (const float*)d_in[1];
  float* scratchA = (float*)d_in[2];  // edge_attr_s2t: 12.8M floats, unused input
  float* scratchB = (float*)d_in[3];  // edge_attr_t2s: 12.8M floats, unused input
  const float* W_l_s2t = (const float*)d_in[4];
  const float* b_s2t   = (const float*)d_in[5];
  const float* W_r_s2t = (const float*)d_in[6];
  const float* W_l_t2s = (const float*)d_in[7];
  const float* b_t2s   = (const float*)d_in[8];
  const float* W_r_t2s = (const float*)d_in[9];
  const float* lin_W   = (const float*)d_in[10];
  const float* lin_b   = (const float*)d_in[11];
  const int* ei_s2t    = (const int*)d_in[12];
  const int* ei_t2s    = (const int*)d_in[13];

  const int NS = in_sizes[0] / FDIM;
  const int NT = in_sizes[1] / FDIM;
  const int E  = in_sizes[12] / 2;
  const int L  = in_sizes[4] / (FDIM * FDIM);
  const size_t NF = (size_t)NS * FDIM;        // 6.4M elems
  const size_t WN = (size_t)L * FDIM * FDIM;  // per weight array, elems

  // scratchA: S0, T0 (bf16 NF), Wb x4, csr_t, csr_s, inv_t, inv_s, off_t, off_s
  unsigned short* S0 = (unsigned short*)scratchA;          // NF bf16
  unsigned short* T0 = S0 + NF;                            // NF bf16
  unsigned short* WbLs2t = T0 + NF;                        // L*4096 bf16
  unsigned short* WbRs2t = WbLs2t + WN;
  unsigned short* WbLt2s = WbRs2t + WN;
  unsigned short* WbRt2s = WbLt2s + WN;
  int*   csr_t  = (int*)(WbRt2s + WN);        // E
  int*   csr_s  = csr_t + E;                  // E
  float* inv_t  = (float*)(csr_s + E);        // NS
  float* inv_s  = inv_t + NS;                 // NS
  int*   off_t  = (int*)(inv_s + NS);         // NS+1
  int*   off_s  = off_t + NS + 1;             // NS+1

  const int NB_T = (NT + 255) >> 8;
  const int NB_S = (NS + 255) >> 8;
  const int B    = (E + 4095) >> 12;

  // scratchB: S1, T1, binned_t, binned_s, H_t, H_s, tot/boff x2
  unsigned short* S1 = (unsigned short*)scratchB;          // NF bf16
  unsigned short* T1 = S1 + NF;                            // NF bf16
  int* binned_t = (int*)(T1 + NF);                         // E
  int* binned_s = binned_t + E;                            // E
  int* H_t      = binned_s + E;                            // B*NB_T
  int* H_s      = H_t + (size_t)B * NB_T;                  // B*NB_S
  int* tot_t    = H_s + (size_t)B * NB_S;                  // 512
  int* boff_t   = tot_t + 512;                             // 512
  int* tot_s    = boff_t + 512;                            // 512
  int* boff_s   = tot_s + 512;                             // 512
  // A_s aliases binned_t+binned_s (dead after build; 2*E*4 == NF*2 bytes)
  unsigned short* As = (unsigned short*)binned_t;

  // d_ws: A_t (bf16 NF) + pooled
  unsigned short* At = (unsigned short*)d_ws;
  float* pooled = (float*)(At + NF);

  const int* src_s2t = ei_s2t;
  const int* dst_s2t = ei_s2t + E;
  const int* src_t2s = ei_t2s;
  const int* dst_t2s = ei_t2s + E;

  // --- CSR build, both directions per pass ---
  hist2_kernel<<<2 * B, 256, 0, stream>>>(dst_s2t, H_t, NB_T, dst_t2s, H_s, NB_S, E, B);
  colscan2_kernel<<<NB_T + NB_S, 256, 0, stream>>>(H_t, tot_t, NB_T, H_s, tot_s, NB_S, B);
  totscan2_kernel<<<2, 256, 0, stream>>>(tot_t, boff_t, NB_T, tot_s, boff_s, NB_S);
  bin2_kernel<<<2 * B, 256, 0, stream>>>(src_s2t, dst_s2t, H_t, boff_t, binned_t, NB_T,
                                         src_t2s, dst_t2s, H_s, boff_s, binned_s, NB_S, E, B);
  build2_kernel<<<NB_T + NB_S, 256, 0, stream>>>(binned_t, boff_t, off_t, csr_t, inv_t, NT, NB_T,
                                                 binned_s, boff_s, off_s, csr_s, inv_s, NS, NB_S, E);

  // --- bf16 packs: features (2 dispatches) + all weights (1 dispatch) ---
  int gP = (int)((NF / 4 + 255) / 256);
  pack_kernel<<<gP, 256, 0, stream>>>(x_source, S0, (int)(NF / 4));
  pack_kernel<<<gP, 256, 0, stream>>>(x_target, T0, (int)(NF / 4));
  int n4W = (int)(WN / 4);
  int gW = (n4W + 255) / 256;
  pack4_kernel<<<4 * gW, 256, 0, stream>>>(W_l_s2t, WbLs2t, W_r_s2t, WbRs2t,
                                           W_l_t2s, WbLt2s, W_r_t2s, WbRt2s, n4W, gW);

  hipMemsetAsync(pooled, 0, 64 * 4, stream);

  unsigned short* xs_in = S0;
  unsigned short* xt_in = T0;
  unsigned short* xs_out = S1;
  unsigned short* xt_out = T1;

  int aT = (NT + 15) / 16;  // agg3 blocks (16 nodes/block)
  int aS = (NS + 15) / 16;
  int gT3 = (NT + 255) / 256;  // fgemm3 blocks (256 rows/block)
  int gS3 = (NS + 255) / 256;

  for (int l = 0; l < L; ++l) {
    const unsigned short* Wl1 = WbLs2t + (size_t)l * 4096;
    const unsigned short* Wr1 = WbRs2t + (size_t)l * 4096;
    const float* bb1 = b_s2t + (size_t)l * 64;
    const unsigned short* Wl2 = WbLt2s + (size_t)l * 4096;
    const unsigned short* Wr2 = WbRt2s + (size_t)l * 4096;
    const float* bb2 = b_t2s + (size_t)l * 64;
    int last = (l == L - 1) ? 1 : 0;

    // A_t = mean_agg(xs_in) over s2t CSR; A_s = mean_agg(xt_in) over t2s CSR
    agg3_kernel<<<aT + aS, 256, 0, stream>>>(xs_in, off_t, csr_t, inv_t, At, NT, aT,
                                             xt_in, off_s, csr_s, inv_s, As, NS);
    // xt_out = A_t@Wl1^T + xt_in@Wr1^T + b1 ; xs_out = A_s@Wl2^T + xs_in@Wr2^T + b2
    fgemm3_kernel<<<gT3 + gS3, 256, 0, stream>>>(At, xt_in, Wl1, Wr1, bb1, xt_out, NT,
                                                 As, xs_in, Wl2, Wr2, bb2, xs_out, NS,
                                                 gT3, pooled, last);

    unsigned short* ts = xs_in; xs_in = xs_out; xs_out = ts;
    unsigned short* tt = xt_in; xt_in = xt_out; xt_out = tt;
  }

  final_kernel<<<1, 64, 0, stream>>>(pooled, lin_W, lin_b, (float*)d_out,
                                     1.0f / (float)(NS + NT));
}

// Round 8
// 500.589 us; speedup vs baseline: 1.4052x; 1.0280x over previous
//
#include <hip/hip_runtime.h>

// BipartiteGNN: 3-layer bipartite SAGEConv + global mean pool + linear.
// NS=NT=100000, E=1.6M per direction, F=H=64.
//
// R15: R14 won (514.6 µs; agg3 group-per-node = 61 µs @ 3.1 TB/s). agg3
// still ILP-starved (VGPR=16: only the 2 unrolled loads in flight; VALU 38%
// + hbm 39% = both pipes half-idle, stalls on vmcnt between load pairs;
// 3.1 TB/s is an outstanding-miss limit, not fabric: L2 ubench 34 TB/s).
// Changes:
//  - agg3 inner loop unroll 2 -> 4 (4 broadcasts + 4 independent uint2
//    loads issued back-to-back); trip counts stay group-uniform;
//  - feature packs merged into one pack2 dispatch.
// Everything else byte-identical to R14 (fgemm3, CSR build, final).

#define FDIM 64

typedef short bh8 __attribute__((ext_vector_type(8)));  // 8 bf16 = 4 VGPR
typedef float fx4 __attribute__((ext_vector_type(4)));  // MFMA accumulator

__device__ __forceinline__ unsigned short f2bf(float f) {
  unsigned int u = __float_as_uint(f);
  unsigned int r = u + 0x7FFFu + ((u >> 16) & 1u);  // round-to-nearest-even
  return (unsigned short)(r >> 16);
}
__device__ __forceinline__ float bf2f(unsigned short h) {
  return __uint_as_float((unsigned int)h << 16);
}

// ---------------- CSR build (bucketed, atomic-free at global scope) ----------------
// Each pass handles BOTH directions in one dispatch (blockIdx selects).

__global__ __launch_bounds__(256) void hist2_kernel(const int* __restrict__ dstT,
                                                    int* __restrict__ HT, int NBT,
                                                    const int* __restrict__ dstS,
                                                    int* __restrict__ HS, int NBS,
                                                    int E, int B) {
  __shared__ int lh[512];
  int b = blockIdx.x;
  const int* dst;
  int* H;
  int NB;
  if (b < B) {
    dst = dstT; H = HT; NB = NBT;
  } else {
    b -= B; dst = dstS; H = HS; NB = NBS;
  }
  int t = threadIdx.x;
  lh[t] = 0;
  lh[t + 256] = 0;
  __syncthreads();
  int base = b * 4096;
#pragma unroll
  for (int i = 0; i < 16; ++i) {
    int e = base + i * 256 + t;
    if (e < E) atomicAdd(&lh[dst[e] >> 8], 1);
  }
  __syncthreads();
  int* row = H + (size_t)b * NB;
  if (t < NB) row[t] = lh[t];
  if (t + 256 < NB) row[t + 256] = lh[t + 256];
}

__global__ __launch_bounds__(256) void colscan2_kernel(int* __restrict__ HT,
                                                       int* __restrict__ totT, int NBT,
                                                       int* __restrict__ HS,
                                                       int* __restrict__ totS, int NBS,
                                                       int B) {
  __shared__ int sh[512];
  int k = blockIdx.x;
  int* H;
  int* tot;
  int NB;
  if (k < NBT) {
    H = HT; tot = totT; NB = NBT;
  } else {
    k -= NBT; H = HS; tot = totS; NB = NBS;
  }
  int t = threadIdx.x;
  int v0 = (t < B) ? H[(size_t)t * NB + k] : 0;
  int v1 = (t + 256 < B) ? H[(size_t)(t + 256) * NB + k] : 0;
  sh[t] = v0;
  sh[t + 256] = v1;
  __syncthreads();
  for (int d = 1; d < 512; d <<= 1) {
    int a0 = (t >= d) ? sh[t - d] : 0;
    int a1 = (t + 256 >= d) ? sh[t + 256 - d] : 0;
    __syncthreads();
    sh[t] += a0;
    sh[t + 256] += a1;
    __syncthreads();
  }
  if (t < B) H[(size_t)t * NB + k] = sh[t] - v0;  // exclusive
  if (t + 256 < B) H[(size_t)(t + 256) * NB + k] = sh[t + 256] - v1;
  if (t == 0) tot[k] = sh[511];
}

__global__ __launch_bounds__(256) void totscan2_kernel(const int* __restrict__ totT,
                                                       int* __restrict__ boffT, int NBT,
                                                       const int* __restrict__ totS,
                                                       int* __restrict__ boffS, int NBS) {
  __shared__ int sh[512];
  const int* tot = (blockIdx.x == 0) ? totT : totS;
  int* boff = (blockIdx.x == 0) ? boffT : boffS;
  int NB = (blockIdx.x == 0) ? NBT : NBS;
  int t = threadIdx.x;
  sh[t] = (t < NB) ? tot[t] : 0;
  sh[t + 256] = (t + 256 < NB) ? tot[t + 256] : 0;
  __syncthreads();
  for (int d = 1; d < 512; d <<= 1) {
    int a0 = (t >= d) ? sh[t - d] : 0;
    int a1 = (t + 256 >= d) ? sh[t + 256 - d] : 0;
    __syncthreads();
    sh[t] += a0;
    sh[t + 256] += a1;
    __syncthreads();
  }
  if (t < NB) boff[t] = (t > 0) ? sh[t - 1] : 0;
  if (t + 256 < NB) boff[t + 256] = sh[t + 255];
}

__global__ __launch_bounds__(256) void bin2_kernel(const int* __restrict__ srcT,
                                                   const int* __restrict__ dstT,
                                                   const int* __restrict__ HT,
                                                   const int* __restrict__ boffT,
                                                   int* __restrict__ binnedT, int NBT,
                                                   const int* __restrict__ srcS,
                                                   const int* __restrict__ dstS,
                                                   const int* __restrict__ HS,
                                                   const int* __restrict__ boffS,
                                                   int* __restrict__ binnedS, int NBS,
                                                   int E, int B) {
  __shared__ int cur[512];
  int b = blockIdx.x;
  const int *src, *dst, *H, *boff;
  int* binned;
  int NB;
  if (b < B) {
    src = srcT; dst = dstT; H = HT; boff = boffT; binned = binnedT; NB = NBT;
  } else {
    b -= B; src = srcS; dst = dstS; H = HS; boff = boffS; binned = binnedS; NB = NBS;
  }
  int t = threadIdx.x;
  const int* row = H + (size_t)b * NB;
  if (t < NB) cur[t] = row[t] + boff[t];
  if (t + 256 < NB) cur[t + 256] = row[t + 256] + boff[t + 256];
  __syncthreads();
  int base = b * 4096;
#pragma unroll
  for (int i = 0; i < 16; ++i) {
    int e = base + i * 256 + t;
    if (e < E) {
      int d = dst[e];
      int p = atomicAdd(&cur[d >> 8], 1);  // LDS atomic
      binned[p] = (src[e] << 8) | (d & 255);
    }
  }
}

__global__ __launch_bounds__(256) void build2_kernel(const int* __restrict__ binnedT,
                                                     const int* __restrict__ boffT,
                                                     int* __restrict__ offT,
                                                     int* __restrict__ csrT,
                                                     float* __restrict__ invT,
                                                     int NT, int NBT,
                                                     const int* __restrict__ binnedS,
                                                     const int* __restrict__ boffS,
                                                     int* __restrict__ offS,
                                                     int* __restrict__ csrS,
                                                     float* __restrict__ invS,
                                                     int NS, int NBS, int E) {
  __shared__ int cnt[256];
  __shared__ int lofs[256];
  __shared__ int cur[256];
  int b = blockIdx.x;
  const int *binned, *boff;
  int *off, *csr;
  float* inv_deg;
  int N, NB;
  if (b < NBT) {
    binned = binnedT; boff = boffT; off = offT; csr = csrT; inv_deg = invT;
    N = NT; NB = NBT;
  } else {
    b -= NBT;
    binned = binnedS; boff = boffS; off = offS; csr = csrS; inv_deg = invS;
    N = NS; NB = NBS;
  }
  int t = threadIdx.x;
  int n0 = b << 8;
  cnt[t] = 0;
  __syncthreads();
  int s0 = boff[b];
  int s1 = (b + 1 < NB) ? boff[b + 1] : E;
  for (int i = s0 + t; i < s1; i += 256) {
    atomicAdd(&cnt[binned[i] & 255], 1);  // LDS atomic
  }
  __syncthreads();
  int c = cnt[t];
  lofs[t] = c;
  __syncthreads();
  for (int d = 1; d < 256; d <<= 1) {
    int v = (t >= d) ? lofs[t - d] : 0;
    __syncthreads();
    lofs[t] += v;
    __syncthreads();
  }
  int excl = lofs[t] - c;
  cur[t] = s0 + excl;
  int node = n0 + t;
  if (node < N) {
    off[node] = s0 + excl;
    inv_deg[node] = 1.0f / (float)max(c, 1);
    if (node == N - 1) off[N] = s0 + excl + c;
  }
  __syncthreads();
  for (int i = s0 + t; i < s1; i += 256) {
    int e = binned[i];
    int r = atomicAdd(&cur[e & 255], 1);  // LDS atomic
    csr[r] = e >> 8;
  }
}

// ---------------- fp32 -> bf16 pack ----------------

// Pack 2 equal-size arrays in one dispatch (features).
__global__ void pack2_kernel(const float* __restrict__ X0, unsigned short* __restrict__ Y0,
                             const float* __restrict__ X1, unsigned short* __restrict__ Y1,
                             int n4, int gPer) {
  int seg = blockIdx.x / gPer;
  int i = (blockIdx.x - seg * gPer) * 256 + threadIdx.x;
  const float* X = seg ? X1 : X0;
  unsigned short* Y = seg ? Y1 : Y0;
  if (i < n4) {
    float4 v = ((const float4*)X)[i];
    uint2 pk;
    pk.x = (unsigned int)f2bf(v.x) | ((unsigned int)f2bf(v.y) << 16);
    pk.y = (unsigned int)f2bf(v.z) | ((unsigned int)f2bf(v.w) << 16);
    ((uint2*)Y)[i] = pk;
  }
}

__global__ void pack4_kernel(const float* __restrict__ X0, unsigned short* __restrict__ Y0,
                             const float* __restrict__ X1, unsigned short* __restrict__ Y1,
                             const float* __restrict__ X2, unsigned short* __restrict__ Y2,
                             const float* __restrict__ X3, unsigned short* __restrict__ Y3,
                             int n4, int gPer) {
  int seg = blockIdx.x / gPer;
  int i = (blockIdx.x - seg * gPer) * 256 + threadIdx.x;
  const float* X = (seg == 0) ? X0 : (seg == 1) ? X1 : (seg == 2) ? X2 : X3;
  unsigned short* Y = (seg == 0) ? Y0 : (seg == 1) ? Y1 : (seg == 2) ? Y2 : Y3;
  if (i < n4) {
    float4 v = ((const float4*)X)[i];
    uint2 pk;
    pk.x = (unsigned int)f2bf(v.x) | ((unsigned int)f2bf(v.y) << 16);
    pk.y = (unsigned int)f2bf(v.z) | ((unsigned int)f2bf(v.w) << 16);
    ((uint2*)Y)[i] = pk;
  }
}

// ---------------- aggregation v3.1: group-per-node, unroll x4 ----------------
// 16 groups of 16 lanes per block; each group owns ONE dst node. Group lane
// fl covers features [fl*4, fl*4+4) via uint2 loads. Row index broadcast
// with width-16 shfl; all control flow group-uniform; shfl sources stay
// in-group. Unroll x4: 4 independent loads in flight per lane.

__global__ __launch_bounds__(256) void agg3_kernel(
    const unsigned short* __restrict__ MsgT, const int* __restrict__ offT,
    const int* __restrict__ csrT, const float* __restrict__ invT,
    unsigned short* __restrict__ AT, int NT, int gT,
    const unsigned short* __restrict__ MsgS, const int* __restrict__ offS,
    const int* __restrict__ csrS, const float* __restrict__ invS,
    unsigned short* __restrict__ AS, int NS) {
  int b = blockIdx.x;
  const unsigned short* Msg;
  const int *off, *csr;
  const float* inv_deg;
  unsigned short* A;
  int N;
  if (b < gT) {
    Msg = MsgT; off = offT; csr = csrT; inv_deg = invT; A = AT; N = NT;
  } else {
    b -= gT;
    Msg = MsgS; off = offS; csr = csrS; inv_deg = invS; A = AS; N = NS;
  }
  int t = threadIdx.x;
  int fl = t & 15;                 // feature sublane within group
  int node = b * 16 + (t >> 4);    // group's dst node
  if (node >= N) return;           // group-uniform
  int s0 = off[node], s1 = off[node + 1];
  float ax = 0.f, ay = 0.f, az = 0.f, aw = 0.f;
  for (int c = s0; c < s1; c += 16) {
    int idx = c + fl;
    int mysrc = (idx < s1) ? csr[idx] : 0;
    int rem = min(16, s1 - c);     // group-uniform
    int j = 0;
    for (; j + 4 <= rem; j += 4) { // unroll x4: 4 loads in flight
      int sa = __shfl(mysrc, j, 16);
      int sb = __shfl(mysrc, j + 1, 16);
      int sc = __shfl(mysrc, j + 2, 16);
      int sd = __shfl(mysrc, j + 3, 16);
      uint2 va = *((const uint2*)(Msg + (size_t)sa * 64) + fl);
      uint2 vb = *((const uint2*)(Msg + (size_t)sb * 64) + fl);
      uint2 vc = *((const uint2*)(Msg + (size_t)sc * 64) + fl);
      uint2 vd = *((const uint2*)(Msg + (size_t)sd * 64) + fl);
      ax += bf2f((unsigned short)(va.x & 0xffffu));
      ay += bf2f((unsigned short)(va.x >> 16));
      az += bf2f((unsigned short)(va.y & 0xffffu));
      aw += bf2f((unsigned short)(va.y >> 16));
      ax += bf2f((unsigned short)(vb.x & 0xffffu));
      ay += bf2f((unsigned short)(vb.x >> 16));
      az += bf2f((unsigned short)(vb.y & 0xffffu));
      aw += bf2f((unsigned short)(vb.y >> 16));
      ax += bf2f((unsigned short)(vc.x & 0xffffu));
      ay += bf2f((unsigned short)(vc.x >> 16));
      az += bf2f((unsigned short)(vc.y & 0xffffu));
      aw += bf2f((unsigned short)(vc.y >> 16));
      ax += bf2f((unsigned short)(vd.x & 0xffffu));
      ay += bf2f((unsigned short)(vd.x >> 16));
      az += bf2f((unsigned short)(vd.y & 0xffffu));
      aw += bf2f((unsigned short)(vd.y >> 16));
    }
    for (; j < rem; ++j) {         // group-uniform tail
      int s = __shfl(mysrc, j, 16);
      uint2 v = *((const uint2*)(Msg + (size_t)s * 64) + fl);
      ax += bf2f((unsigned short)(v.x & 0xffffu));
      ay += bf2f((unsigned short)(v.x >> 16));
      az += bf2f((unsigned short)(v.y & 0xffffu));
      aw += bf2f((unsigned short)(v.y >> 16));
    }
  }
  float id = inv_deg[node];
  uint2 pk;
  pk.x = (unsigned int)f2bf(ax * id) | ((unsigned int)f2bf(ay * id) << 16);
  pk.y = (unsigned int)f2bf(az * id) | ((unsigned int)f2bf(aw * id) << 16);
  *((uint2*)(A + (size_t)node * 64) + fl) = pk;
}

// ---------------- MFMA dual GEMM v3 (both directions, one dispatch) ----------------
// R13-proven: block = 4 waves x 64 rows = 256 rows; weights staged once per
// block with coalesced linear uint4 reads, LDS pre-permuted so frag f =
// wlds[f*64+lane] (lane-contiguous conflict-free ds_read_b128); 16 frags in
// registers across 4 subtiles; next-subtile A/X prefetch; C staged through
// per-wave LDS f32 tile -> coalesced dwordx4 stores; pooled epilogue last.

__global__ __launch_bounds__(256) void fgemm3_kernel(
    const unsigned short* __restrict__ A1, const unsigned short* __restrict__ X1,
    const unsigned short* __restrict__ Wl1, const unsigned short* __restrict__ Wr1,
    const float* __restrict__ bias1, unsigned short* __restrict__ Y1, int N1,
    const unsigned short* __restrict__ A2, const unsigned short* __restrict__ X2,
    const unsigned short* __restrict__ Wl2, const unsigned short* __restrict__ Wr2,
    const float* __restrict__ bias2, unsigned short* __restrict__ Y2, int N2,
    int g1, float* __restrict__ pooled, int lastLayer) {
  __shared__ __align__(16) uint4 wlds[1024];      // 16KB: frag f at [f*64+lane]
  __shared__ __align__(16) float cst[4][16][68];  // 17.4KB: per-wave C transpose
  __shared__ float pacc[64];
  int bid = blockIdx.x;
  const unsigned short *A, *X, *Wlb, *Wrb;
  const float* bias;
  unsigned short* Y;
  int N;
  if (bid < g1) {
    A = A1; X = X1; Wlb = Wl1; Wrb = Wr1; bias = bias1; Y = Y1; N = N1;
  } else {
    bid -= g1;
    A = A2; X = X2; Wlb = Wl2; Wrb = Wr2; bias = bias2; Y = Y2; N = N2;
  }
  int t = threadIdx.x;
  if (lastLayer && t < 64) pacc[t] = 0.f;

  // ---- coalesced weight staging with frag permutation ----
  // chunk c (16B) of Wl||Wr: op=c>>9, row=(c&511)>>3, ch8=c&7
  // -> frag f = op*8 + (ch8>>2)*4 + (row>>4), lane = (ch8&3)*16 + (row&15)
#pragma unroll
  for (int p = 0; p < 4; ++p) {
    int c = p * 256 + t;
    int op = c >> 9;
    int c9 = c & 511;
    int row = c9 >> 3;
    int ch8 = c9 & 7;
    const unsigned short* W = op ? Wrb : Wlb;
    uint4 v = *(const uint4*)(W + row * 64 + ch8 * 8);
    int f = op * 8 + (ch8 >> 2) * 4 + (row >> 4);
    wlds[f * 64 + (ch8 & 3) * 16 + (row & 15)] = v;
  }

  int wid = t >> 6, lane = t & 63;
  int lr = lane & 15;  // row within A/B frags; col (=h low) within C
  int kg = lane >> 4;  // k-subgroup 0..3
  int w0 = bid * 256 + wid * 64;  // this wave's first row

  float bias_r[4];
#pragma unroll
  for (int nt = 0; nt < 4; ++nt) bias_r[nt] = bias[nt * 16 + lr];

  __syncthreads();  // weights visible

  union UB { uint4 u; bh8 v; };
  // all 16 weight fragments -> registers, reused by all 4 subtiles
  UB bl0[4], bl1[4], br0[4], br1[4];
#pragma unroll
  for (int nt = 0; nt < 4; ++nt) {
    bl0[nt].u = wlds[(0 + nt) * 64 + lane];   // Wl, k 0..31
    bl1[nt].u = wlds[(4 + nt) * 64 + lane];   // Wl, k 32..63
    br0[nt].u = wlds[(8 + nt) * 64 + lane];   // Wr, k 0..31
    br1[nt].u = wlds[(12 + nt) * 64 + lane];  // Wr, k 32..63
  }

  // prefetch subtile 0
  int mr = min(w0 + lr, N - 1);
  const bh8* ar = (const bh8*)(A + (size_t)mr * 64);
  const bh8* xr = (const bh8*)(X + (size_t)mr * 64);
  bh8 a0 = ar[kg], a1 = ar[4 + kg], x0 = xr[kg], x1 = xr[4 + kg];

  float psum[4] = {0.f, 0.f, 0.f, 0.f};

#pragma unroll
  for (int sub = 0; sub < 4; ++sub) {
    bh8 na0 = a0, na1 = a1, nx0 = x0, nx1 = x1;
    if (sub < 3) {  // prefetch next subtile under this one's MFMAs
      int mrn = min(w0 + (sub + 1) * 16 + lr, N - 1);
      const bh8* arn = (const bh8*)(A + (size_t)mrn * 64);
      const bh8* xrn = (const bh8*)(X + (size_t)mrn * 64);
      na0 = arn[kg]; na1 = arn[4 + kg]; nx0 = xrn[kg]; nx1 = xrn[4 + kg];
    }
    fx4 acc[4];
#pragma unroll
    for (int nt = 0; nt < 4; ++nt) acc[nt] = (fx4){0.f, 0.f, 0.f, 0.f};
#pragma unroll
    for (int nt = 0; nt < 4; ++nt)
      acc[nt] = __builtin_amdgcn_mfma_f32_16x16x32_bf16(a0, bl0[nt].v, acc[nt], 0, 0, 0);
#pragma unroll
    for (int nt = 0; nt < 4; ++nt)
      acc[nt] = __builtin_amdgcn_mfma_f32_16x16x32_bf16(a1, bl1[nt].v, acc[nt], 0, 0, 0);
#pragma unroll
    for (int nt = 0; nt < 4; ++nt)
      acc[nt] = __builtin_amdgcn_mfma_f32_16x16x32_bf16(x0, br0[nt].v, acc[nt], 0, 0, 0);
#pragma unroll
    for (int nt = 0; nt < 4; ++nt)
      acc[nt] = __builtin_amdgcn_mfma_f32_16x16x32_bf16(x1, br1[nt].v, acc[nt], 0, 0, 0);

    int mbase = w0 + sub * 16;
    if (!lastLayer) {
      // stage C (bias added) into per-wave tile: row = kg*4+j, col = h
#pragma unroll
      for (int nt = 0; nt < 4; ++nt)
#pragma unroll
        for (int j = 0; j < 4; ++j)
          cst[wid][kg * 4 + j][nt * 16 + lr] = acc[nt][j] + bias_r[nt];
      // per-wave tile readback (R11-proven; same wave, no barrier needed)
#pragma unroll
      for (int s = 0; s < 2; ++s) {
        int idx = lane + 64 * s;  // 16 rows x 8 chunks of 8 h
        int r = idx >> 3, c = idx & 7;
        float4 v0 = *(const float4*)&cst[wid][r][c * 8];
        float4 v1 = *(const float4*)&cst[wid][r][c * 8 + 4];
        uint4 pk;
        pk.x = (unsigned int)f2bf(v0.x) | ((unsigned int)f2bf(v0.y) << 16);
        pk.y = (unsigned int)f2bf(v0.z) | ((unsigned int)f2bf(v0.w) << 16);
        pk.z = (unsigned int)f2bf(v1.x) | ((unsigned int)f2bf(v1.y) << 16);
        pk.w = (unsigned int)f2bf(v1.z) | ((unsigned int)f2bf(v1.w) << 16);
        int m = mbase + r;
        if (m < N) ((uint4*)(Y + (size_t)m * 64))[c] = pk;
      }
    } else {
      // pooled-only epilogue: no Y write
#pragma unroll
      for (int nt = 0; nt < 4; ++nt) {
#pragma unroll
        for (int j = 0; j < 4; ++j) {
          int m = mbase + kg * 4 + j;
          if (m < N) psum[nt] += acc[nt][j] + bias_r[nt];
        }
      }
    }
    a0 = na0; a1 = na1; x0 = nx0; x1 = nx1;
  }

  if (lastLayer) {
#pragma unroll
    for (int nt = 0; nt < 4; ++nt) atomicAdd(&pacc[nt * 16 + lr], psum[nt]);
    __syncthreads();
    if (t < 64) atomicAdd(&pooled[t], pacc[t]);
  }
}

// ---------------- final linear ----------------

__global__ void final_kernel(const float* __restrict__ pooled, const float* __restrict__ linW,
                             const float* __restrict__ linb, float* __restrict__ out, float invM) {
  int t = threadIdx.x;  // 64 threads
  float v = pooled[t] * invM * linW[t];
#pragma unroll
  for (int o = 32; o > 0; o >>= 1) v += __shfl_down(v, o, 64);
  if (t == 0) out[0] = v + linb[0];
}

// ---------------- launch ----------------

extern "C" void kernel_launch(void* const* d_in, const int* in_sizes, int n_in,
                              void* d_out, int out_size, void* d_ws, size_t ws_size,
                              hipStream_t stream) {
  const float* x_source = (const float*)d_in[0];
  const float* x_target = (const float*)d_in[1];
  float* scratchA = (float*)d_in[2];  // edge_attr_s2t: 12.8M floats, unused input
  float* scratchB = (float*)d_in[3];  // edge_attr_t2s: 12.8M floats, unused input
  const float* W_l_s2t = (const float*)d_in[4];
  const float* b_s2t   = (const float*)d_in[5];
  const float* W_r_s2t = (const float*)d_in[6];
  const float* W_l_t2s = (const float*)d_in[7];
  const float* b_t2s   = (const float*)d_in[8];
  const float* W_r_t2s = (const float*)d_in[9];
  const float* lin_W   = (const float*)d_in[10];
  const float* lin_b   = (const float*)d_in[11];
  const int* ei_s2t    = (const int*)d_in[12];
  const int* ei_t2s    = (const int*)d_in[13];

  const int NS = in_sizes[0] / FDIM;
  const int NT = in_sizes[1] / FDIM;
  const int E  = in_sizes[12] / 2;
  const int L  = in_sizes[4] / (FDIM * FDIM);
  const size_t NF = (size_t)NS * FDIM;        // 6.4M elems
  const size_t WN = (size_t)L * FDIM * FDIM;  // per weight array, elems

  // scratchA: S0, T0 (bf16 NF), Wb x4, csr_t, csr_s, inv_t, inv_s, off_t, off_s
  unsigned short* S0 = (unsigned short*)scratchA;          // NF bf16
  unsigned short* T0 = S0 + NF;                            // NF bf16
  unsigned short* WbLs2t = T0 + NF;                        // L*4096 bf16
  unsigned short* WbRs2t = WbLs2t + WN;
  unsigned short* WbLt2s = WbRs2t + WN;
  unsigned short* WbRt2s = WbLt2s + WN;
  int*   csr_t  = (int*)(WbRt2s + WN);        // E
  int*   csr_s  = csr_t + E;                  // E
  float* inv_t  = (float*)(csr_s + E);        // NS
  float* inv_s  = inv_t + NS;                 // NS
  int*   off_t  = (int*)(inv_s + NS);         // NS+1
  int*   off_s  = off_t + NS + 1;             // NS+1

  const int NB_T = (NT + 255) >> 8;
  const int NB_S = (NS + 255) >> 8;
  const int B    = (E + 4095) >> 12;

  // scratchB: S1, T1, binned_t, binned_s, H_t, H_s, tot/boff x2
  unsigned short* S1 = (unsigned short*)scratchB;          // NF bf16
  unsigned short* T1 = S1 + NF;                            // NF bf16
  int* binned_t = (int*)(T1 + NF);                         // E
  int* binned_s = binned_t + E;                            // E
  int* H_t      = binned_s + E;                            // B*NB_T
  int* H_s      = H_t + (size_t)B * NB_T;                  // B*NB_S
  int* tot_t    = H_s + (size_t)B * NB_S;                  // 512
  int* boff_t   = tot_t + 512;                             // 512
  int* tot_s    = boff_t + 512;                            // 512
  int* boff_s   = tot_s + 512;                             // 512
  // A_s aliases binned_t+binned_s (dead after build; 2*E*4 == NF*2 bytes)
  unsigned short* As = (unsigned short*)binned_t;

  // d_ws: A_t (bf16 NF) + pooled
  unsigned short* At = (unsigned short*)d_ws;
  float* pooled = (float*)(At + NF);

  const int* src_s2t = ei_s2t;
  const int* dst_s2t = ei_s2t + E;
  const int* src_t2s = ei_t2s;
  const int* dst_t2s = ei_t2s + E;

  // --- CSR build, both directions per pass ---
  hist2_kernel<<<2 * B, 256, 0, stream>>>(dst_s2t, H_t, NB_T, dst_t2s, H_s, NB_S, E, B);
  colscan2_kernel<<<NB_T + NB_S, 256, 0, stream>>>(H_t, tot_t, NB_T, H_s, tot_s, NB_S, B);
  totscan2_kernel<<<2, 256, 0, stream>>>(tot_t, boff_t, NB_T, tot_s, boff_s, NB_S);
  bin2_kernel<<<2 * B, 256, 0, stream>>>(src_s2t, dst_s2t, H_t, boff_t, binned_t, NB_T,
                                         src_t2s, dst_t2s, H_s, boff_s, binned_s, NB_S, E, B);
  build2_kernel<<<NB_T + NB_S, 256, 0, stream>>>(binned_t, boff_t, off_t, csr_t, inv_t, NT, NB_T,
                                                 binned_s, boff_s, off_s, csr_s, inv_s, NS, NB_S, E);

  // --- bf16 packs: features (1 dispatch) + all weights (1 dispatch) ---
  int n4F = (int)(NF / 4);
  int gP = (n4F + 255) / 256;
  pack2_kernel<<<2 * gP, 256, 0, stream>>>(x_source, S0, x_target, T0, n4F, gP);
  int n4W = (int)(WN / 4);
  int gW = (n4W + 255) / 256;
  pack4_kernel<<<4 * gW, 256, 0, stream>>>(W_l_s2t, WbLs2t, W_r_s2t, WbRs2t,
                                           W_l_t2s, WbLt2s, W_r_t2s, WbRt2s, n4W, gW);

  hipMemsetAsync(pooled, 0, 64 * 4, stream);

  unsigned short* xs_in = S0;
  unsigned short* xt_in = T0;
  unsigned short* xs_out = S1;
  unsigned short* xt_out = T1;

  int aT = (NT + 15) / 16;  // agg3 blocks (16 nodes/block)
  int aS = (NS + 15) / 16;
  int gT3 = (NT + 255) / 256;  // fgemm3 blocks (256 rows/block)
  int gS3 = (NS + 255) / 256;

  for (int l = 0; l < L; ++l) {
    const unsigned short* Wl1 = WbLs2t + (size_t)l * 4096;
    const unsigned short* Wr1 = WbRs2t + (size_t)l * 4096;
    const float* bb1 = b_s2t + (size_t)l * 64;
    const unsigned short* Wl2 = WbLt2s + (size_t)l * 4096;
    const unsigned short* Wr2 = WbRt2s + (size_t)l * 4096;
    const float* bb2 = b_t2s + (size_t)l * 64;
    int last = (l == L - 1) ? 1 : 0;

    // A_t = mean_agg(xs_in) over s2t CSR; A_s = mean_agg(xt_in) over t2s CSR
    agg3_kernel<<<aT + aS, 256, 0, stream>>>(xs_in, off_t, csr_t, inv_t, At, NT, aT,
                                             xt_in, off_s, csr_s, inv_s, As, NS);
    // xt_out = A_t@Wl1^T + xt_in@Wr1^T + b1 ; xs_out = A_s@Wl2^T + xs_in@Wr2^T + b2
    fgemm3_kernel<<<gT3 + gS3, 256, 0, stream>>>(At, xt_in, Wl1, Wr1, bb1, xt_out, NT,
                                                 As, xs_in, Wl2, Wr2, bb2, xs_out, NS,
                                                 gT3, pooled, last);

    unsigned short* ts = xs_in; xs_in = xs_out; xs_out = ts;
    unsigned short* tt = xt_in; xt_in = xt_out; xt_out = tt;
  }

  final_kernel<<<1, 64, 0, stream>>>(pooled, lin_W, lin_b, (float*)d_out,
                                     1.0f / (float)(NS + NT));
}

// Round 10
// 479.672 us; speedup vs baseline: 1.4665x; 1.0436x over previous
//
#include <hip/hip_runtime.h>

// BipartiteGNN: 3-layer bipartite SAGEConv + global mean pool + linear.
// NS=NT=100000, E=1.6M per direction, F=H=64.
//
// R17 == R16 resubmit (R16 bench was an infra failure: "container failed
// twice", no counters). Audit of the new bin2 found no OOB/hang/LDS-overflow
// candidate (binary-search bucket lookup proven in-range; lsort scatter
// bounded by construction).
//
// R16: R15 won (500.6 µs; agg3 < 60 µs, out of top-5). New top kernel:
// bin2 = 61 µs with WRITE_SIZE 74 MB for a 6.4 MB payload (11x write
// amplification: 64 lanes scatter 4B entries to 64 different bucket-cursor
// runs -> 64 dirty lines per store instr; VALU 1.4%, occ 25% = pure
// write-transaction-bound). Fix: LDS counting-sort per block, then copy
// out piecewise-contiguous runs:
//   local hist -> local excl scan -> LDS scatter (lsort[4096]) ->
//   linear copy-out, bucket found by 9-step binary search over loff;
//   consecutive threads write consecutive local indices -> destinations
//   monotone/piecewise-consecutive (~7 lines/wave vs 64).
// Only bin2 changes; agg3/fgemm3/build/packs byte-identical to R15.

#define FDIM 64

typedef short bh8 __attribute__((ext_vector_type(8)));  // 8 bf16 = 4 VGPR
typedef float fx4 __attribute__((ext_vector_type(4)));  // MFMA accumulator

__device__ __forceinline__ unsigned short f2bf(float f) {
  unsigned int u = __float_as_uint(f);
  unsigned int r = u + 0x7FFFu + ((u >> 16) & 1u);  // round-to-nearest-even
  return (unsigned short)(r >> 16);
}
__device__ __forceinline__ float bf2f(unsigned short h) {
  return __uint_as_float((unsigned int)h << 16);
}

// ---------------- CSR build (bucketed, atomic-free at global scope) ----------------
// Each pass handles BOTH directions in one dispatch (blockIdx selects).

__global__ __launch_bounds__(256) void hist2_kernel(const int* __restrict__ dstT,
                                                    int* __restrict__ HT, int NBT,
                                                    const int* __restrict__ dstS,
                                                    int* __restrict__ HS, int NBS,
                                                    int E, int B) {
  __shared__ int lh[512];
  int b = blockIdx.x;
  const int* dst;
  int* H;
  int NB;
  if (b < B) {
    dst = dstT; H = HT; NB = NBT;
  } else {
    b -= B; dst = dstS; H = HS; NB = NBS;
  }
  int t = threadIdx.x;
  lh[t] = 0;
  lh[t + 256] = 0;
  __syncthreads();
  int base = b * 4096;
#pragma unroll
  for (int i = 0; i < 16; ++i) {
    int e = base + i * 256 + t;
    if (e < E) atomicAdd(&lh[dst[e] >> 8], 1);
  }
  __syncthreads();
  int* row = H + (size_t)b * NB;
  if (t < NB) row[t] = lh[t];
  if (t + 256 < NB) row[t + 256] = lh[t + 256];
}

__global__ __launch_bounds__(256) void colscan2_kernel(int* __restrict__ HT,
                                                       int* __restrict__ totT, int NBT,
                                                       int* __restrict__ HS,
                                                       int* __restrict__ totS, int NBS,
                                                       int B) {
  __shared__ int sh[512];
  int k = blockIdx.x;
  int* H;
  int* tot;
  int NB;
  if (k < NBT) {
    H = HT; tot = totT; NB = NBT;
  } else {
    k -= NBT; H = HS; tot = totS; NB = NBS;
  }
  int t = threadIdx.x;
  int v0 = (t < B) ? H[(size_t)t * NB + k] : 0;
  int v1 = (t + 256 < B) ? H[(size_t)(t + 256) * NB + k] : 0;
  sh[t] = v0;
  sh[t + 256] = v1;
  __syncthreads();
  for (int d = 1; d < 512; d <<= 1) {
    int a0 = (t >= d) ? sh[t - d] : 0;
    int a1 = (t + 256 >= d) ? sh[t + 256 - d] : 0;
    __syncthreads();
    sh[t] += a0;
    sh[t + 256] += a1;
    __syncthreads();
  }
  if (t < B) H[(size_t)t * NB + k] = sh[t] - v0;  // exclusive
  if (t + 256 < B) H[(size_t)(t + 256) * NB + k] = sh[t + 256] - v1;
  if (t == 0) tot[k] = sh[511];
}

__global__ __launch_bounds__(256) void totscan2_kernel(const int* __restrict__ totT,
                                                       int* __restrict__ boffT, int NBT,
                                                       const int* __restrict__ totS,
                                                       int* __restrict__ boffS, int NBS) {
  __shared__ int sh[512];
  const int* tot = (blockIdx.x == 0) ? totT : totS;
  int* boff = (blockIdx.x == 0) ? boffT : boffS;
  int NB = (blockIdx.x == 0) ? NBT : NBS;
  int t = threadIdx.x;
  sh[t] = (t < NB) ? tot[t] : 0;
  sh[t + 256] = (t + 256 < NB) ? tot[t + 256] : 0;
  __syncthreads();
  for (int d = 1; d < 512; d <<= 1) {
    int a0 = (t >= d) ? sh[t - d] : 0;
    int a1 = (t + 256 >= d) ? sh[t + 256 - d] : 0;
    __syncthreads();
    sh[t] += a0;
    sh[t + 256] += a1;
    __syncthreads();
  }
  if (t < NB) boff[t] = (t > 0) ? sh[t - 1] : 0;
  if (t + 256 < NB) boff[t + 256] = sh[t + 255];
}

// Pass 3 (R16): LDS counting-sort per 4096-edge block, then coalesced-run
// copy-out. Destinations are monotone piecewise-consecutive (block's run in
// bucket k is contiguous at gbase[k] = H[b][k] + boff[k]).
__global__ __launch_bounds__(256) void bin2_kernel(const int* __restrict__ srcT,
                                                   const int* __restrict__ dstT,
                                                   const int* __restrict__ HT,
                                                   const int* __restrict__ boffT,
                                                   int* __restrict__ binnedT, int NBT,
                                                   const int* __restrict__ srcS,
                                                   const int* __restrict__ dstS,
                                                   const int* __restrict__ HS,
                                                   const int* __restrict__ boffS,
                                                   int* __restrict__ binnedS, int NBS,
                                                   int E, int B) {
  __shared__ int lsort[4096];  // 16KB: locally bucket-sorted packed entries
  __shared__ int ssc[512];     // scan buffer (counts -> inclusive scan)
  __shared__ int loff[512];    // exclusive local offsets per bucket
  __shared__ int lcur[512];    // local cursors
  __shared__ int gbase[512];   // global base of this block's run per bucket
  int b = blockIdx.x;
  const int *src, *dst, *H, *boff;
  int* binned;
  int NB;
  if (b < B) {
    src = srcT; dst = dstT; H = HT; boff = boffT; binned = binnedT; NB = NBT;
  } else {
    b -= B; src = srcS; dst = dstS; H = HS; boff = boffS; binned = binnedS; NB = NBS;
  }
  int t = threadIdx.x;
  const int* row = H + (size_t)b * NB;
  gbase[t] = (t < NB) ? (row[t] + boff[t]) : 0;
  gbase[t + 256] = (t + 256 < NB) ? (row[t + 256] + boff[t + 256]) : 0;
  ssc[t] = 0;
  ssc[t + 256] = 0;
  __syncthreads();
  int base = b * 4096;
  int m = min(4096, E - base);
  // local histogram
#pragma unroll
  for (int i = 0; i < 16; ++i) {
    int e = base + i * 256 + t;
    if (e < E) atomicAdd(&ssc[dst[e] >> 8], 1);
  }
  __syncthreads();
  // exclusive scan of counts -> loff; init cursors
  int v0 = ssc[t], v1 = ssc[t + 256];
  for (int d = 1; d < 512; d <<= 1) {
    int a0 = (t >= d) ? ssc[t - d] : 0;
    int a1 = (t + 256 >= d) ? ssc[t + 256 - d] : 0;
    __syncthreads();
    ssc[t] += a0;
    ssc[t + 256] += a1;
    __syncthreads();
  }
  loff[t] = ssc[t] - v0;
  loff[t + 256] = ssc[t + 256] - v1;
  lcur[t] = loff[t];
  lcur[t + 256] = loff[t + 256];
  __syncthreads();
  // scatter into LDS (counting sort)
#pragma unroll
  for (int i = 0; i < 16; ++i) {
    int e = base + i * 256 + t;
    if (e < E) {
      int d = dst[e];
      int p = atomicAdd(&lcur[d >> 8], 1);  // LDS atomic
      lsort[p] = (src[e] << 8) | (d & 255);
    }
  }
  __syncthreads();
  // copy-out: thread handles local index i; bucket via binary search
  // (largest k with loff[k] <= i; zero-count buckets never maximal)
  for (int i = t; i < m; i += 256) {
    int lo = 0, hi = 511;
    while (lo < hi) {
      int mid = (lo + hi + 1) >> 1;
      if (loff[mid] <= i) lo = mid; else hi = mid - 1;
    }
    binned[gbase[lo] + (i - loff[lo])] = lsort[i];
  }
}

__global__ __launch_bounds__(256) void build2_kernel(const int* __restrict__ binnedT,
                                                     const int* __restrict__ boffT,
                                                     int* __restrict__ offT,
                                                     int* __restrict__ csrT,
                                                     float* __restrict__ invT,
                                                     int NT, int NBT,
                                                     const int* __restrict__ binnedS,
                                                     const int* __restrict__ boffS,
                                                     int* __restrict__ offS,
                                                     int* __restrict__ csrS,
                                                     float* __restrict__ invS,
                                                     int NS, int NBS, int E) {
  __shared__ int cnt[256];
  __shared__ int lofs[256];
  __shared__ int cur[256];
  int b = blockIdx.x;
  const int *binned, *boff;
  int *off, *csr;
  float* inv_deg;
  int N, NB;
  if (b < NBT) {
    binned = binnedT; boff = boffT; off = offT; csr = csrT; inv_deg = invT;
    N = NT; NB = NBT;
  } else {
    b -= NBT;
    binned = binnedS; boff = boffS; off = offS; csr = csrS; inv_deg = invS;
    N = NS; NB = NBS;
  }
  int t = threadIdx.x;
  int n0 = b << 8;
  cnt[t] = 0;
  __syncthreads();
  int s0 = boff[b];
  int s1 = (b + 1 < NB) ? boff[b + 1] : E;
  for (int i = s0 + t; i < s1; i += 256) {
    atomicAdd(&cnt[binned[i] & 255], 1);  // LDS atomic
  }
  __syncthreads();
  int c = cnt[t];
  lofs[t] = c;
  __syncthreads();
  for (int d = 1; d < 256; d <<= 1) {
    int v = (t >= d) ? lofs[t - d] : 0;
    __syncthreads();
    lofs[t] += v;
    __syncthreads();
  }
  int excl = lofs[t] - c;
  cur[t] = s0 + excl;
  int node = n0 + t;
  if (node < N) {
    off[node] = s0 + excl;
    inv_deg[node] = 1.0f / (float)max(c, 1);
    if (node == N - 1) off[N] = s0 + excl + c;
  }
  __syncthreads();
  for (int i = s0 + t; i < s1; i += 256) {
    int e = binned[i];
    int r = atomicAdd(&cur[e & 255], 1);  // LDS atomic
    csr[r] = e >> 8;
  }
}

// ---------------- fp32 -> bf16 pack ----------------

// Pack 2 equal-size arrays in one dispatch (features).
__global__ void pack2_kernel(const float* __restrict__ X0, unsigned short* __restrict__ Y0,
                             const float* __restrict__ X1, unsigned short* __restrict__ Y1,
                             int n4, int gPer) {
  int seg = blockIdx.x / gPer;
  int i = (blockIdx.x - seg * gPer) * 256 + threadIdx.x;
  const float* X = seg ? X1 : X0;
  unsigned short* Y = seg ? Y1 : Y0;
  if (i < n4) {
    float4 v = ((const float4*)X)[i];
    uint2 pk;
    pk.x = (unsigned int)f2bf(v.x) | ((unsigned int)f2bf(v.y) << 16);
    pk.y = (unsigned int)f2bf(v.z) | ((unsigned int)f2bf(v.w) << 16);
    ((uint2*)Y)[i] = pk;
  }
}

__global__ void pack4_kernel(const float* __restrict__ X0, unsigned short* __restrict__ Y0,
                             const float* __restrict__ X1, unsigned short* __restrict__ Y1,
                             const float* __restrict__ X2, unsigned short* __restrict__ Y2,
                             const float* __restrict__ X3, unsigned short* __restrict__ Y3,
                             int n4, int gPer) {
  int seg = blockIdx.x / gPer;
  int i = (blockIdx.x - seg * gPer) * 256 + threadIdx.x;
  const float* X = (seg == 0) ? X0 : (seg == 1) ? X1 : (seg == 2) ? X2 : X3;
  unsigned short* Y = (seg == 0) ? Y0 : (seg == 1) ? Y1 : (seg == 2) ? Y2 : Y3;
  if (i < n4) {
    float4 v = ((const float4*)X)[i];
    uint2 pk;
    pk.x = (unsigned int)f2bf(v.x) | ((unsigned int)f2bf(v.y) << 16);
    pk.y = (unsigned int)f2bf(v.z) | ((unsigned int)f2bf(v.w) << 16);
    ((uint2*)Y)[i] = pk;
  }
}

// ---------------- aggregation v3.1: group-per-node, unroll x4 (R15-proven) ----------------

__global__ __launch_bounds__(256) void agg3_kernel(
    const unsigned short* __restrict__ MsgT, const int* __restrict__ offT,
    const int* __restrict__ csrT, const float* __restrict__ invT,
    unsigned short* __restrict__ AT, int NT, int gT,
    const unsigned short* __restrict__ MsgS, const int* __restrict__ offS,
    const int* __restrict__ csrS, const float* __restrict__ invS,
    unsigned short* __restrict__ AS, int NS) {
  int b = blockIdx.x;
  const unsigned short* Msg;
  const int *off, *csr;
  const float* inv_deg;
  unsigned short* A;
  int N;
  if (b < gT) {
    Msg = MsgT; off = offT; csr = csrT; inv_deg = invT; A = AT; N = NT;
  } else {
    b -= gT;
    Msg = MsgS; off = offS; csr = csrS; inv_deg = invS; A = AS; N = NS;
  }
  int t = threadIdx.x;
  int fl = t & 15;                 // feature sublane within group
  int node = b * 16 + (t >> 4);    // group's dst node
  if (node >= N) return;           // group-uniform
  int s0 = off[node], s1 = off[node + 1];
  float ax = 0.f, ay = 0.f, az = 0.f, aw = 0.f;
  for (int c = s0; c < s1; c += 16) {
    int idx = c + fl;
    int mysrc = (idx < s1) ? csr[idx] : 0;
    int rem = min(16, s1 - c);     // group-uniform
    int j = 0;
    for (; j + 4 <= rem; j += 4) { // unroll x4: 4 loads in flight
      int sa = __shfl(mysrc, j, 16);
      int sb = __shfl(mysrc, j + 1, 16);
      int sc = __shfl(mysrc, j + 2, 16);
      int sd = __shfl(mysrc, j + 3, 16);
      uint2 va = *((const uint2*)(Msg + (size_t)sa * 64) + fl);
      uint2 vb = *((const uint2*)(Msg + (size_t)sb * 64) + fl);
      uint2 vc = *((const uint2*)(Msg + (size_t)sc * 64) + fl);
      uint2 vd = *((const uint2*)(Msg + (size_t)sd * 64) + fl);
      ax += bf2f((unsigned short)(va.x & 0xffffu));
      ay += bf2f((unsigned short)(va.x >> 16));
      az += bf2f((unsigned short)(va.y & 0xffffu));
      aw += bf2f((unsigned short)(va.y >> 16));
      ax += bf2f((unsigned short)(vb.x & 0xffffu));
      ay += bf2f((unsigned short)(vb.x >> 16));
      az += bf2f((unsigned short)(vb.y & 0xffffu));
      aw += bf2f((unsigned short)(vb.y >> 16));
      ax += bf2f((unsigned short)(vc.x & 0xffffu));
      ay += bf2f((unsigned short)(vc.x >> 16));
      az += bf2f((unsigned short)(vc.y & 0xffffu));
      aw += bf2f((unsigned short)(vc.y >> 16));
      ax += bf2f((unsigned short)(vd.x & 0xffffu));
      ay += bf2f((unsigned short)(vd.x >> 16));
      az += bf2f((unsigned short)(vd.y & 0xffffu));
      aw += bf2f((unsigned short)(vd.y >> 16));
    }
    for (; j < rem; ++j) {         // group-uniform tail
      int s = __shfl(mysrc, j, 16);
      uint2 v = *((const uint2*)(Msg + (size_t)s * 64) + fl);
      ax += bf2f((unsigned short)(v.x & 0xffffu));
      ay += bf2f((unsigned short)(v.x >> 16));
      az += bf2f((unsigned short)(v.y & 0xffffu));
      aw += bf2f((unsigned short)(v.y >> 16));
    }
  }
  float id = inv_deg[node];
  uint2 pk;
  pk.x = (unsigned int)f2bf(ax * id) | ((unsigned int)f2bf(ay * id) << 16);
  pk.y = (unsigned int)f2bf(az * id) | ((unsigned int)f2bf(aw * id) << 16);
  *((uint2*)(A + (size_t)node * 64) + fl) = pk;
}

// ---------------- MFMA dual GEMM v3 (both directions, one dispatch) ----------------
// R13-proven: block = 4 waves x 64 rows = 256 rows; weights staged once per
// block with coalesced linear uint4 reads, LDS pre-permuted so frag f =
// wlds[f*64+lane] (lane-contiguous conflict-free ds_read_b128); 16 frags in
// registers across 4 subtiles; next-subtile A/X prefetch; C staged through
// per-wave LDS f32 tile -> coalesced dwordx4 stores; pooled epilogue last.

__global__ __launch_bounds__(256) void fgemm3_kernel(
    const unsigned short* __restrict__ A1, const unsigned short* __restrict__ X1,
    const unsigned short* __restrict__ Wl1, const unsigned short* __restrict__ Wr1,
    const float* __restrict__ bias1, unsigned short* __restrict__ Y1, int N1,
    const unsigned short* __restrict__ A2, const unsigned short* __restrict__ X2,
    const unsigned short* __restrict__ Wl2, const unsigned short* __restrict__ Wr2,
    const float* __restrict__ bias2, unsigned short* __restrict__ Y2, int N2,
    int g1, float* __restrict__ pooled, int lastLayer) {
  __shared__ __align__(16) uint4 wlds[1024];      // 16KB: frag f at [f*64+lane]
  __shared__ __align__(16) float cst[4][16][68];  // 17.4KB: per-wave C transpose
  __shared__ float pacc[64];
  int bid = blockIdx.x;
  const unsigned short *A, *X, *Wlb, *Wrb;
  const float* bias;
  unsigned short* Y;
  int N;
  if (bid < g1) {
    A = A1; X = X1; Wlb = Wl1; Wrb = Wr1; bias = bias1; Y = Y1; N = N1;
  } else {
    bid -= g1;
    A = A2; X = X2; Wlb = Wl2; Wrb = Wr2; bias = bias2; Y = Y2; N = N2;
  }
  int t = threadIdx.x;
  if (lastLayer && t < 64) pacc[t] = 0.f;

  // ---- coalesced weight staging with frag permutation ----
  // chunk c (16B) of Wl||Wr: op=c>>9, row=(c&511)>>3, ch8=c&7
  // -> frag f = op*8 + (ch8>>2)*4 + (row>>4), lane = (ch8&3)*16 + (row&15)
#pragma unroll
  for (int p = 0; p < 4; ++p) {
    int c = p * 256 + t;
    int op = c >> 9;
    int c9 = c & 511;
    int row = c9 >> 3;
    int ch8 = c9 & 7;
    const unsigned short* W = op ? Wrb : Wlb;
    uint4 v = *(const uint4*)(W + row * 64 + ch8 * 8);
    int f = op * 8 + (ch8 >> 2) * 4 + (row >> 4);
    wlds[f * 64 + (ch8 & 3) * 16 + (row & 15)] = v;
  }

  int wid = t >> 6, lane = t & 63;
  int lr = lane & 15;  // row within A/B frags; col (=h low) within C
  int kg = lane >> 4;  // k-subgroup 0..3
  int w0 = bid * 256 + wid * 64;  // this wave's first row

  float bias_r[4];
#pragma unroll
  for (int nt = 0; nt < 4; ++nt) bias_r[nt] = bias[nt * 16 + lr];

  __syncthreads();  // weights visible

  union UB { uint4 u; bh8 v; };
  // all 16 weight fragments -> registers, reused by all 4 subtiles
  UB bl0[4], bl1[4], br0[4], br1[4];
#pragma unroll
  for (int nt = 0; nt < 4; ++nt) {
    bl0[nt].u = wlds[(0 + nt) * 64 + lane];   // Wl, k 0..31
    bl1[nt].u = wlds[(4 + nt) * 64 + lane];   // Wl, k 32..63
    br0[nt].u = wlds[(8 + nt) * 64 + lane];   // Wr, k 0..31
    br1[nt].u = wlds[(12 + nt) * 64 + lane];  // Wr, k 32..63
  }

  // prefetch subtile 0
  int mr = min(w0 + lr, N - 1);
  const bh8* ar = (const bh8*)(A + (size_t)mr * 64);
  const bh8* xr = (const bh8*)(X + (size_t)mr * 64);
  bh8 a0 = ar[kg], a1 = ar[4 + kg], x0 = xr[kg], x1 = xr[4 + kg];

  float psum[4] = {0.f, 0.f, 0.f, 0.f};

#pragma unroll
  for (int sub = 0; sub < 4; ++sub) {
    bh8 na0 = a0, na1 = a1, nx0 = x0, nx1 = x1;
    if (sub < 3) {  // prefetch next subtile under this one's MFMAs
      int mrn = min(w0 + (sub + 1) * 16 + lr, N - 1);
      const bh8* arn = (const bh8*)(A + (size_t)mrn * 64);
      const bh8* xrn = (const bh8*)(X + (size_t)mrn * 64);
      na0 = arn[kg]; na1 = arn[4 + kg]; nx0 = xrn[kg]; nx1 = xrn[4 + kg];
    }
    fx4 acc[4];
#pragma unroll
    for (int nt = 0; nt < 4; ++nt) acc[nt] = (fx4){0.f, 0.f, 0.f, 0.f};
#pragma unroll
    for (int nt = 0; nt < 4; ++nt)
      acc[nt] = __builtin_amdgcn_mfma_f32_16x16x32_bf16(a0, bl0[nt].v, acc[nt], 0, 0, 0);
#pragma unroll
    for (int nt = 0; nt < 4; ++nt)
      acc[nt] = __builtin_amdgcn_mfma_f32_16x16x32_bf16(a1, bl1[nt].v, acc[nt], 0, 0, 0);
#pragma unroll
    for (int nt = 0; nt < 4; ++nt)
      acc[nt] = __builtin_amdgcn_mfma_f32_16x16x32_bf16(x0, br0[nt].v, acc[nt], 0, 0, 0);
#pragma unroll
    for (int nt = 0; nt < 4; ++nt)
      acc[nt] = __builtin_amdgcn_mfma_f32_16x16x32_bf16(x1, br1[nt].v, acc[nt], 0, 0, 0);

    int mbase = w0 + sub * 16;
    if (!lastLayer) {
      // stage C (bias added) into per-wave tile: row = kg*4+j, col = h
#pragma unroll
      for (int nt = 0; nt < 4; ++nt)
#pragma unroll
        for (int j = 0; j < 4; ++j)
          cst[wid][kg * 4 + j][nt * 16 + lr] = acc[nt][j] + bias_r[nt];
      // per-wave tile readback (R11-proven; same wave, no barrier needed)
#pragma unroll
      for (int s = 0; s < 2; ++s) {
        int idx = lane + 64 * s;  // 16 rows x 8 chunks of 8 h
        int r = idx >> 3, c = idx & 7;
        float4 v0 = *(const float4*)&cst[wid][r][c * 8];
        float4 v1 = *(const float4*)&cst[wid][r][c * 8 + 4];
        uint4 pk;
        pk.x = (unsigned int)f2bf(v0.x) | ((unsigned int)f2bf(v0.y) << 16);
        pk.y = (unsigned int)f2bf(v0.z) | ((unsigned int)f2bf(v0.w) << 16);
        pk.z = (unsigned int)f2bf(v1.x) | ((unsigned int)f2bf(v1.y) << 16);
        pk.w = (unsigned int)f2bf(v1.z) | ((unsigned int)f2bf(v1.w) << 16);
        int m = mbase + r;
        if (m < N) ((uint4*)(Y + (size_t)m * 64))[c] = pk;
      }
    } else {
      // pooled-only epilogue: no Y write
#pragma unroll
      for (int nt = 0; nt < 4; ++nt) {
#pragma unroll
        for (int j = 0; j < 4; ++j) {
          int m = mbase + kg * 4 + j;
          if (m < N) psum[nt] += acc[nt][j] + bias_r[nt];
        }
      }
    }
    a0 = na0; a1 = na1; x0 = nx0; x1 = nx1;
  }

  if (lastLayer) {
#pragma unroll
    for (int nt = 0; nt < 4; ++nt) atomicAdd(&pacc[nt * 16 + lr], psum[nt]);
    __syncthreads();
    if (t < 64) atomicAdd(&pooled[t], pacc[t]);
  }
}

// ---------------- final linear ----------------

__global__ void final_kernel(const float* __restrict__ pooled, const float* __restrict__ linW,
                             const float* __restrict__ linb, float* __restrict__ out, float invM) {
  int t = threadIdx.x;  // 64 threads
  float v = pooled[t] * invM * linW[t];
#pragma unroll
  for (int o = 32; o > 0; o >>= 1) v += __shfl_down(v, o, 64);
  if (t == 0) out[0] = v + linb[0];
}

// ---------------- launch ----------------

extern "C" void kernel_launch(void* const* d_in, const int* in_sizes, int n_in,
                              void* d_out, int out_size, void* d_ws, size_t ws_size,
                              hipStream_t stream) {
  const float* x_source = (const float*)d_in[0];
  const float* x_target = (const float*)d_in[1];
  float* scratchA = (float*)d_in[2];  // edge_attr_s2t: 12.8M floats, unused input
  float* scratchB = (float*)d_in[3];  // edge_attr_t2s: 12.8M floats, unused input
  const float* W_l_s2t = (const float*)d_in[4];
  const float* b_s2t   = (const float*)d_in[5];
  const float* W_r_s2t = (const float*)d_in[6];
  const float* W_l_t2s = (const float*)d_in[7];
  const float* b_t2s   = (const float*)d_in[8];
  const float* W_r_t2s = (const float*)d_in[9];
  const float* lin_W   = (const float*)d_in[10];
  const float* lin_b   = (const float*)d_in[11];
  const int* ei_s2t    = (const int*)d_in[12];
  const int* ei_t2s    = (const int*)d_in[13];

  const int NS = in_sizes[0] / FDIM;
  const int NT = in_sizes[1] / FDIM;
  const int E  = in_sizes[12] / 2;
  const int L  = in_sizes[4] / (FDIM * FDIM);
  const size_t NF = (size_t)NS * FDIM;        // 6.4M elems
  const size_t WN = (size_t)L * FDIM * FDIM;  // per weight array, elems

  // scratchA: S0, T0 (bf16 NF), Wb x4, csr_t, csr_s, inv_t, inv_s, off_t, off_s
  unsigned short* S0 = (unsigned short*)scratchA;          // NF bf16
  unsigned short* T0 = S0 + NF;                            // NF bf16
  unsigned short* WbLs2t = T0 + NF;                        // L*4096 bf16
  unsigned short* WbRs2t = WbLs2t + WN;
  unsigned short* WbLt2s = WbRs2t + WN;
  unsigned short* WbRt2s = WbLt2s + WN;
  int*   csr_t  = (int*)(WbRt2s + WN);        // E
  int*   csr_s  = csr_t + E;                  // E
  float* inv_t  = (float*)(csr_s + E);        // NS
  float* inv_s  = inv_t + NS;                 // NS
  int*   off_t  = (int*)(inv_s + NS);         // NS+1
  int*   off_s  = off_t + NS + 1;             // NS+1

  const int NB_T = (NT + 255) >> 8;
  const int NB_S = (NS + 255) >> 8;
  const int B    = (E + 4095) >> 12;

  // scratchB: S1, T1, binned_t, binned_s, H_t, H_s, tot/boff x2
  unsigned short* S1 = (unsigned short*)scratchB;          // NF bf16
  unsigned short* T1 = S1 + NF;                            // NF bf16
  int* binned_t = (int*)(T1 + NF);                         // E
  int* binned_s = binned_t + E;                            // E
  int* H_t      = binned_s + E;                            // B*NB_T
  int* H_s      = H_t + (size_t)B * NB_T;                  // B*NB_S
  int* tot_t    = H_s + (size_t)B * NB_S;                  // 512
  int* boff_t   = tot_t + 512;                             // 512
  int* tot_s    = boff_t + 512;                            // 512
  int* boff_s   = tot_s + 512;                             // 512
  // A_s aliases binned_t+binned_s (dead after build; 2*E*4 == NF*2 bytes)
  unsigned short* As = (unsigned short*)binned_t;

  // d_ws: A_t (bf16 NF) + pooled
  unsigned short* At = (unsigned short*)d_ws;
  float* pooled = (float*)(At + NF);

  const int* src_s2t = ei_s2t;
  const int* dst_s2t = ei_s2t + E;
  const int* src_t2s = ei_t2s;
  const int* dst_t2s = ei_t2s + E;

  // --- CSR build, both directions per pass ---
  hist2_kernel<<<2 * B, 256, 0, stream>>>(dst_s2t, H_t, NB_T, dst_t2s, H_s, NB_S, E, B);
  colscan2_kernel<<<NB_T + NB_S, 256, 0, stream>>>(H_t, tot_t, NB_T, H_s, tot_s, NB_S, B);
  totscan2_kernel<<<2, 256, 0, stream>>>(tot_t, boff_t, NB_T, tot_s, boff_s, NB_S);
  bin2_kernel<<<2 * B, 256, 0, stream>>>(src_s2t, dst_s2t, H_t, boff_t, binned_t, NB_T,
                                         src_t2s, dst_t2s, H_s, boff_s, binned_s, NB_S, E, B);
  build2_kernel<<<NB_T + NB_S, 256, 0, stream>>>(binned_t, boff_t, off_t, csr_t, inv_t, NT, NB_T,
                                                 binned_s, boff_s, off_s, csr_s, inv_s, NS, NB_S, E);

  // --- bf16 packs: features (1 dispatch) + all weights (1 dispatch) ---
  int n4F = (int)(NF / 4);
  int gP = (n4F + 255) / 256;
  pack2_kernel<<<2 * gP, 256, 0, stream>>>(x_source, S0, x_target, T0, n4F, gP);
  int n4W = (int)(WN / 4);
  int gW = (n4W + 255) / 256;
  pack4_kernel<<<4 * gW, 256, 0, stream>>>(W_l_s2t, WbLs2t, W_r_s2t, WbRs2t,
                                           W_l_t2s, WbLt2s, W_r_t2s, WbRt2s, n4W, gW);

  hipMemsetAsync(pooled, 0, 64 * 4, stream);

  unsigned short* xs_in = S0;
  unsigned short* xt_in = T0;
  unsigned short* xs_out = S1;
  unsigned short* xt_out = T1;

  int aT = (NT + 15) / 16;  // agg3 blocks (16 nodes/block)
  int aS = (NS + 15) / 16;
  int gT3 = (NT + 255) / 256;  // fgemm3 blocks (256 rows/block)
  int gS3 = (NS + 255) / 256;

  for (int l = 0; l < L; ++l) {
    const unsigned short* Wl1 = WbLs2t + (size_t)l * 4096;
    const unsigned short* Wr1 = WbRs2t + (size_t)l * 4096;
    const float* bb1 = b_s2t + (size_t)l * 64;
    const unsigned short* Wl2 = WbLt2s + (size_t)l * 4096;
    const unsigned short* Wr2 = WbRt2s + (size_t)l * 4096;
    const float* bb2 = b_t2s + (size_t)l * 64;
    int last = (l == L - 1) ? 1 : 0;

    // A_t = mean_agg(xs_in) over s2t CSR; A_s = mean_agg(xt_in) over t2s CSR
    agg3_kernel<<<aT + aS, 256, 0, stream>>>(xs_in, off_t, csr_t, inv_t, At, NT, aT,
                                             xt_in, off_s, csr_s, inv_s, As, NS);
    // xt_out = A_t@Wl1^T + xt_in@Wr1^T + b1 ; xs_out = A_s@Wl2^T + xs_in@Wr2^T + b2
    fgemm3_kernel<<<gT3 + gS3, 256, 0, stream>>>(At, xt_in, Wl1, Wr1, bb1, xt_out, NT,
                                                 As, xs_in, Wl2, Wr2, bb2, xs_out, NS,
                                                 gT3, pooled, last);

    unsigned short* ts = xs_in; xs_in = xs_out; xs_out = ts;
    unsigned short* tt = xt_in; xt_in = xt_out; xt_out = tt;
  }

  final_kernel<<<1, 64, 0, stream>>>(pooled, lin_W, lin_b, (float*)d_out,
                                     1.0f / (float)(NS + NT));
}

// Round 11
// 471.629 us; speedup vs baseline: 1.4915x; 1.0171x over previous
//
#include <hip/hip_runtime.h>

// BipartiteGNN: 3-layer bipartite SAGEConv + global mean pool + linear.
// NS=NT=100000, E=1.6M per direction, F=H=64.
//
// R18: R17 won (479.7 µs; bin2 counting-sort out of top-5). agg3 unroll x4
// under-delivered (61 -> 57.3, predicted 48-55): per-lane MLP exhausted.
// Refined model: delivered BW 7.1 TB/s << 34.5 L2 ceiling, VALU 39% -> the
// limiter is REQUEST RATE (one wave-load per 128B row, 3.2M rows/dispatch).
// agg4: uint4 loads (16B/lane) -> 8 lanes cover a row, each group
// instruction gathers TWO rows (half=lane>>3 selects row j+2k+half, fq=
// lane&7 selects the 16B feature chunk). Halves load-instruction count at
// identical bytes. 8 rows/iter = 4 dual-row loads in flight (same MLP depth
// as R17). Tail: clamped shfl index + predicated accumulate (trip counts
// group-uniform, shfl in-group -> R14 discipline). Cross-half reduce =
// one shfl_down(8,16); lanes 0-7 store uint4 (128B/node coalesced).
// Everything else byte-identical to R17.

#define FDIM 64

typedef short bh8 __attribute__((ext_vector_type(8)));  // 8 bf16 = 4 VGPR
typedef float fx4 __attribute__((ext_vector_type(4)));  // MFMA accumulator

__device__ __forceinline__ unsigned short f2bf(float f) {
  unsigned int u = __float_as_uint(f);
  unsigned int r = u + 0x7FFFu + ((u >> 16) & 1u);  // round-to-nearest-even
  return (unsigned short)(r >> 16);
}
__device__ __forceinline__ float bf2f(unsigned short h) {
  return __uint_as_float((unsigned int)h << 16);
}

// ---------------- CSR build (bucketed, atomic-free at global scope) ----------------
// Each pass handles BOTH directions in one dispatch (blockIdx selects).

__global__ __launch_bounds__(256) void hist2_kernel(const int* __restrict__ dstT,
                                                    int* __restrict__ HT, int NBT,
                                                    const int* __restrict__ dstS,
                                                    int* __restrict__ HS, int NBS,
                                                    int E, int B) {
  __shared__ int lh[512];
  int b = blockIdx.x;
  const int* dst;
  int* H;
  int NB;
  if (b < B) {
    dst = dstT; H = HT; NB = NBT;
  } else {
    b -= B; dst = dstS; H = HS; NB = NBS;
  }
  int t = threadIdx.x;
  lh[t] = 0;
  lh[t + 256] = 0;
  __syncthreads();
  int base = b * 4096;
#pragma unroll
  for (int i = 0; i < 16; ++i) {
    int e = base + i * 256 + t;
    if (e < E) atomicAdd(&lh[dst[e] >> 8], 1);
  }
  __syncthreads();
  int* row = H + (size_t)b * NB;
  if (t < NB) row[t] = lh[t];
  if (t + 256 < NB) row[t + 256] = lh[t + 256];
}

__global__ __launch_bounds__(256) void colscan2_kernel(int* __restrict__ HT,
                                                       int* __restrict__ totT, int NBT,
                                                       int* __restrict__ HS,
                                                       int* __restrict__ totS, int NBS,
                                                       int B) {
  __shared__ int sh[512];
  int k = blockIdx.x;
  int* H;
  int* tot;
  int NB;
  if (k < NBT) {
    H = HT; tot = totT; NB = NBT;
  } else {
    k -= NBT; H = HS; tot = totS; NB = NBS;
  }
  int t = threadIdx.x;
  int v0 = (t < B) ? H[(size_t)t * NB + k] : 0;
  int v1 = (t + 256 < B) ? H[(size_t)(t + 256) * NB + k] : 0;
  sh[t] = v0;
  sh[t + 256] = v1;
  __syncthreads();
  for (int d = 1; d < 512; d <<= 1) {
    int a0 = (t >= d) ? sh[t - d] : 0;
    int a1 = (t + 256 >= d) ? sh[t + 256 - d] : 0;
    __syncthreads();
    sh[t] += a0;
    sh[t + 256] += a1;
    __syncthreads();
  }
  if (t < B) H[(size_t)t * NB + k] = sh[t] - v0;  // exclusive
  if (t + 256 < B) H[(size_t)(t + 256) * NB + k] = sh[t + 256] - v1;
  if (t == 0) tot[k] = sh[511];
}

__global__ __launch_bounds__(256) void totscan2_kernel(const int* __restrict__ totT,
                                                       int* __restrict__ boffT, int NBT,
                                                       const int* __restrict__ totS,
                                                       int* __restrict__ boffS, int NBS) {
  __shared__ int sh[512];
  const int* tot = (blockIdx.x == 0) ? totT : totS;
  int* boff = (blockIdx.x == 0) ? boffT : boffS;
  int NB = (blockIdx.x == 0) ? NBT : NBS;
  int t = threadIdx.x;
  sh[t] = (t < NB) ? tot[t] : 0;
  sh[t + 256] = (t + 256 < NB) ? tot[t + 256] : 0;
  __syncthreads();
  for (int d = 1; d < 512; d <<= 1) {
    int a0 = (t >= d) ? sh[t - d] : 0;
    int a1 = (t + 256 >= d) ? sh[t + 256 - d] : 0;
    __syncthreads();
    sh[t] += a0;
    sh[t + 256] += a1;
    __syncthreads();
  }
  if (t < NB) boff[t] = (t > 0) ? sh[t - 1] : 0;
  if (t + 256 < NB) boff[t + 256] = sh[t + 255];
}

// Pass 3 (R16-proven): LDS counting-sort per 4096-edge block, then
// coalesced-run copy-out (destinations monotone piecewise-consecutive).
__global__ __launch_bounds__(256) void bin2_kernel(const int* __restrict__ srcT,
                                                   const int* __restrict__ dstT,
                                                   const int* __restrict__ HT,
                                                   const int* __restrict__ boffT,
                                                   int* __restrict__ binnedT, int NBT,
                                                   const int* __restrict__ srcS,
                                                   const int* __restrict__ dstS,
                                                   const int* __restrict__ HS,
                                                   const int* __restrict__ boffS,
                                                   int* __restrict__ binnedS, int NBS,
                                                   int E, int B) {
  __shared__ int lsort[4096];  // 16KB: locally bucket-sorted packed entries
  __shared__ int ssc[512];     // scan buffer (counts -> inclusive scan)
  __shared__ int loff[512];    // exclusive local offsets per bucket
  __shared__ int lcur[512];    // local cursors
  __shared__ int gbase[512];   // global base of this block's run per bucket
  int b = blockIdx.x;
  const int *src, *dst, *H, *boff;
  int* binned;
  int NB;
  if (b < B) {
    src = srcT; dst = dstT; H = HT; boff = boffT; binned = binnedT; NB = NBT;
  } else {
    b -= B; src = srcS; dst = dstS; H = HS; boff = boffS; binned = binnedS; NB = NBS;
  }
  int t = threadIdx.x;
  const int* row = H + (size_t)b * NB;
  gbase[t] = (t < NB) ? (row[t] + boff[t]) : 0;
  gbase[t + 256] = (t + 256 < NB) ? (row[t + 256] + boff[t + 256]) : 0;
  ssc[t] = 0;
  ssc[t + 256] = 0;
  __syncthreads();
  int base = b * 4096;
  int m = min(4096, E - base);
  // local histogram
#pragma unroll
  for (int i = 0; i < 16; ++i) {
    int e = base + i * 256 + t;
    if (e < E) atomicAdd(&ssc[dst[e] >> 8], 1);
  }
  __syncthreads();
  // exclusive scan of counts -> loff; init cursors
  int v0 = ssc[t], v1 = ssc[t + 256];
  for (int d = 1; d < 512; d <<= 1) {
    int a0 = (t >= d) ? ssc[t - d] : 0;
    int a1 = (t + 256 >= d) ? ssc[t + 256 - d] : 0;
    __syncthreads();
    ssc[t] += a0;
    ssc[t + 256] += a1;
    __syncthreads();
  }
  loff[t] = ssc[t] - v0;
  loff[t + 256] = ssc[t + 256] - v1;
  lcur[t] = loff[t];
  lcur[t + 256] = loff[t + 256];
  __syncthreads();
  // scatter into LDS (counting sort)
#pragma unroll
  for (int i = 0; i < 16; ++i) {
    int e = base + i * 256 + t;
    if (e < E) {
      int d = dst[e];
      int p = atomicAdd(&lcur[d >> 8], 1);  // LDS atomic
      lsort[p] = (src[e] << 8) | (d & 255);
    }
  }
  __syncthreads();
  // copy-out: thread handles local index i; bucket via binary search
  for (int i = t; i < m; i += 256) {
    int lo = 0, hi = 511;
    while (lo < hi) {
      int mid = (lo + hi + 1) >> 1;
      if (loff[mid] <= i) lo = mid; else hi = mid - 1;
    }
    binned[gbase[lo] + (i - loff[lo])] = lsort[i];
  }
}

__global__ __launch_bounds__(256) void build2_kernel(const int* __restrict__ binnedT,
                                                     const int* __restrict__ boffT,
                                                     int* __restrict__ offT,
                                                     int* __restrict__ csrT,
                                                     float* __restrict__ invT,
                                                     int NT, int NBT,
                                                     const int* __restrict__ binnedS,
                                                     const int* __restrict__ boffS,
                                                     int* __restrict__ offS,
                                                     int* __restrict__ csrS,
                                                     float* __restrict__ invS,
                                                     int NS, int NBS, int E) {
  __shared__ int cnt[256];
  __shared__ int lofs[256];
  __shared__ int cur[256];
  int b = blockIdx.x;
  const int *binned, *boff;
  int *off, *csr;
  float* inv_deg;
  int N, NB;
  if (b < NBT) {
    binned = binnedT; boff = boffT; off = offT; csr = csrT; inv_deg = invT;
    N = NT; NB = NBT;
  } else {
    b -= NBT;
    binned = binnedS; boff = boffS; off = offS; csr = csrS; inv_deg = invS;
    N = NS; NB = NBS;
  }
  int t = threadIdx.x;
  int n0 = b << 8;
  cnt[t] = 0;
  __syncthreads();
  int s0 = boff[b];
  int s1 = (b + 1 < NB) ? boff[b + 1] : E;
  for (int i = s0 + t; i < s1; i += 256) {
    atomicAdd(&cnt[binned[i] & 255], 1);  // LDS atomic
  }
  __syncthreads();
  int c = cnt[t];
  lofs[t] = c;
  __syncthreads();
  for (int d = 1; d < 256; d <<= 1) {
    int v = (t >= d) ? lofs[t - d] : 0;
    __syncthreads();
    lofs[t] += v;
    __syncthreads();
  }
  int excl = lofs[t] - c;
  cur[t] = s0 + excl;
  int node = n0 + t;
  if (node < N) {
    off[node] = s0 + excl;
    inv_deg[node] = 1.0f / (float)max(c, 1);
    if (node == N - 1) off[N] = s0 + excl + c;
  }
  __syncthreads();
  for (int i = s0 + t; i < s1; i += 256) {
    int e = binned[i];
    int r = atomicAdd(&cur[e & 255], 1);  // LDS atomic
    csr[r] = e >> 8;
  }
}

// ---------------- fp32 -> bf16 pack ----------------

// Pack 2 equal-size arrays in one dispatch (features).
__global__ void pack2_kernel(const float* __restrict__ X0, unsigned short* __restrict__ Y0,
                             const float* __restrict__ X1, unsigned short* __restrict__ Y1,
                             int n4, int gPer) {
  int seg = blockIdx.x / gPer;
  int i = (blockIdx.x - seg * gPer) * 256 + threadIdx.x;
  const float* X = seg ? X1 : X0;
  unsigned short* Y = seg ? Y1 : Y0;
  if (i < n4) {
    float4 v = ((const float4*)X)[i];
    uint2 pk;
    pk.x = (unsigned int)f2bf(v.x) | ((unsigned int)f2bf(v.y) << 16);
    pk.y = (unsigned int)f2bf(v.z) | ((unsigned int)f2bf(v.w) << 16);
    ((uint2*)Y)[i] = pk;
  }
}

__global__ void pack4_kernel(const float* __restrict__ X0, unsigned short* __restrict__ Y0,
                             const float* __restrict__ X1, unsigned short* __restrict__ Y1,
                             const float* __restrict__ X2, unsigned short* __restrict__ Y2,
                             const float* __restrict__ X3, unsigned short* __restrict__ Y3,
                             int n4, int gPer) {
  int seg = blockIdx.x / gPer;
  int i = (blockIdx.x - seg * gPer) * 256 + threadIdx.x;
  const float* X = (seg == 0) ? X0 : (seg == 1) ? X1 : (seg == 2) ? X2 : X3;
  unsigned short* Y = (seg == 0) ? Y0 : (seg == 1) ? Y1 : (seg == 2) ? Y2 : Y3;
  if (i < n4) {
    float4 v = ((const float4*)X)[i];
    uint2 pk;
    pk.x = (unsigned int)f2bf(v.x) | ((unsigned int)f2bf(v.y) << 16);
    pk.y = (unsigned int)f2bf(v.z) | ((unsigned int)f2bf(v.w) << 16);
    ((uint2*)Y)[i] = pk;
  }
}

// ---------------- aggregation v4: dual-row uint4 gather ----------------
// 16 groups of 16 lanes per block; each group owns ONE dst node. Within a
// group: half = lane>>3 selects which of TWO rows this lane reads; fq =
// lane&7 selects the 16B feature chunk. One group-wide uint4 load gathers
// 2 full 128B rows -> half the load instructions of agg3 at equal bytes.
// 8 rows per unrolled iter (4 dual-row loads in flight). Tail uses clamped
// shfl index + predicated accumulate. Cross-half reduce: shfl_down(8,16).
// Trip counts group-uniform; shfl sources in-group (R14 discipline).

__global__ __launch_bounds__(256) void agg4_kernel(
    const unsigned short* __restrict__ MsgT, const int* __restrict__ offT,
    const int* __restrict__ csrT, const float* __restrict__ invT,
    unsigned short* __restrict__ AT, int NT, int gT,
    const unsigned short* __restrict__ MsgS, const int* __restrict__ offS,
    const int* __restrict__ csrS, const float* __restrict__ invS,
    unsigned short* __restrict__ AS, int NS) {
  int b = blockIdx.x;
  const unsigned short* Msg;
  const int *off, *csr;
  const float* inv_deg;
  unsigned short* A;
  int N;
  if (b < gT) {
    Msg = MsgT; off = offT; csr = csrT; inv_deg = invT; A = AT; N = NT;
  } else {
    b -= gT;
    Msg = MsgS; off = offS; csr = csrS; inv_deg = invS; A = AS; N = NS;
  }
  int t = threadIdx.x;
  int fl = t & 15;                 // lane within group
  int half = fl >> 3;              // row selector (0/1) within a pair
  int fq = fl & 7;                 // feature chunk: features [fq*8, fq*8+8)
  int node = b * 16 + (t >> 4);    // group's dst node
  if (node >= N) return;           // group-uniform
  int s0 = off[node], s1 = off[node + 1];
  float a0 = 0.f, a1 = 0.f, a2 = 0.f, a3 = 0.f;
  float a4 = 0.f, a5 = 0.f, a6 = 0.f, a7 = 0.f;
  for (int c = s0; c < s1; c += 16) {
    int idx = c + fl;
    int mysrc = (idx < s1) ? csr[idx] : 0;
    int rem = min(16, s1 - c);     // group-uniform
    int j = 0;
    for (; j + 8 <= rem; j += 8) { // 8 rows: 4 dual-row loads in flight
      int sA = __shfl(mysrc, j + 0 + half, 16);
      int sB = __shfl(mysrc, j + 2 + half, 16);
      int sC = __shfl(mysrc, j + 4 + half, 16);
      int sD = __shfl(mysrc, j + 6 + half, 16);
      uint4 vA = *((const uint4*)(Msg + (size_t)sA * 64) + fq);
      uint4 vB = *((const uint4*)(Msg + (size_t)sB * 64) + fq);
      uint4 vC = *((const uint4*)(Msg + (size_t)sC * 64) + fq);
      uint4 vD = *((const uint4*)(Msg + (size_t)sD * 64) + fq);
      a0 += bf2f((unsigned short)(vA.x & 0xffffu));
      a1 += bf2f((unsigned short)(vA.x >> 16));
      a2 += bf2f((unsigned short)(vA.y & 0xffffu));
      a3 += bf2f((unsigned short)(vA.y >> 16));
      a4 += bf2f((unsigned short)(vA.z & 0xffffu));
      a5 += bf2f((unsigned short)(vA.z >> 16));
      a6 += bf2f((unsigned short)(vA.w & 0xffffu));
      a7 += bf2f((unsigned short)(vA.w >> 16));
      a0 += bf2f((unsigned short)(vB.x & 0xffffu));
      a1 += bf2f((unsigned short)(vB.x >> 16));
      a2 += bf2f((unsigned short)(vB.y & 0xffffu));
      a3 += bf2f((unsigned short)(vB.y >> 16));
      a4 += bf2f((unsigned short)(vB.z & 0xffffu));
      a5 += bf2f((unsigned short)(vB.z >> 16));
      a6 += bf2f((unsigned short)(vB.w & 0xffffu));
      a7 += bf2f((unsigned short)(vB.w >> 16));
      a0 += bf2f((unsigned short)(vC.x & 0xffffu));
      a1 += bf2f((unsigned short)(vC.x >> 16));
      a2 += bf2f((unsigned short)(vC.y & 0xffffu));
      a3 += bf2f((unsigned short)(vC.y >> 16));
      a4 += bf2f((unsigned short)(vC.z & 0xffffu));
      a5 += bf2f((unsigned short)(vC.z >> 16));
      a6 += bf2f((unsigned short)(vC.w & 0xffffu));
      a7 += bf2f((unsigned short)(vC.w >> 16));
      a0 += bf2f((unsigned short)(vD.x & 0xffffu));
      a1 += bf2f((unsigned short)(vD.x >> 16));
      a2 += bf2f((unsigned short)(vD.y & 0xffffu));
      a3 += bf2f((unsigned short)(vD.y >> 16));
      a4 += bf2f((unsigned short)(vD.z & 0xffffu));
      a5 += bf2f((unsigned short)(vD.z >> 16));
      a6 += bf2f((unsigned short)(vD.w & 0xffffu));
      a7 += bf2f((unsigned short)(vD.w >> 16));
    }
    for (; j < rem; j += 2) {      // pair tail (+ possible odd last row)
      int r = j + half;
      bool valid = r < rem;
      int s = __shfl(mysrc, valid ? r : (rem - 1), 16);  // in-range, in-group
      uint4 v = *((const uint4*)(Msg + (size_t)s * 64) + fq);
      if (valid) {
        a0 += bf2f((unsigned short)(v.x & 0xffffu));
        a1 += bf2f((unsigned short)(v.x >> 16));
        a2 += bf2f((unsigned short)(v.y & 0xffffu));
        a3 += bf2f((unsigned short)(v.y >> 16));
        a4 += bf2f((unsigned short)(v.z & 0xffffu));
        a5 += bf2f((unsigned short)(v.z >> 16));
        a6 += bf2f((unsigned short)(v.w & 0xffffu));
        a7 += bf2f((unsigned short)(v.w >> 16));
      }
    }
  }
  // cross-half reduce: lane l (<8) += lane l+8 (width-16 segments)
  a0 += __shfl_down(a0, 8, 16);
  a1 += __shfl_down(a1, 8, 16);
  a2 += __shfl_down(a2, 8, 16);
  a3 += __shfl_down(a3, 8, 16);
  a4 += __shfl_down(a4, 8, 16);
  a5 += __shfl_down(a5, 8, 16);
  a6 += __shfl_down(a6, 8, 16);
  a7 += __shfl_down(a7, 8, 16);
  if (half == 0) {
    float id = inv_deg[node];
    uint4 pk;
    pk.x = (unsigned int)f2bf(a0 * id) | ((unsigned int)f2bf(a1 * id) << 16);
    pk.y = (unsigned int)f2bf(a2 * id) | ((unsigned int)f2bf(a3 * id) << 16);
    pk.z = (unsigned int)f2bf(a4 * id) | ((unsigned int)f2bf(a5 * id) << 16);
    pk.w = (unsigned int)f2bf(a6 * id) | ((unsigned int)f2bf(a7 * id) << 16);
    ((uint4*)(A + (size_t)node * 64))[fq] = pk;
  }
}

// ---------------- MFMA dual GEMM v3 (both directions, one dispatch) ----------------
// R13-proven: block = 4 waves x 64 rows = 256 rows; weights staged once per
// block with coalesced linear uint4 reads, LDS pre-permuted so frag f =
// wlds[f*64+lane] (lane-contiguous conflict-free ds_read_b128); 16 frags in
// registers across 4 subtiles; next-subtile A/X prefetch; C staged through
// per-wave LDS f32 tile -> coalesced dwordx4 stores; pooled epilogue last.

__global__ __launch_bounds__(256) void fgemm3_kernel(
    const unsigned short* __restrict__ A1, const unsigned short* __restrict__ X1,
    const unsigned short* __restrict__ Wl1, const unsigned short* __restrict__ Wr1,
    const float* __restrict__ bias1, unsigned short* __restrict__ Y1, int N1,
    const unsigned short* __restrict__ A2, const unsigned short* __restrict__ X2,
    const unsigned short* __restrict__ Wl2, const unsigned short* __restrict__ Wr2,
    const float* __restrict__ bias2, unsigned short* __restrict__ Y2, int N2,
    int g1, float* __restrict__ pooled, int lastLayer) {
  __shared__ __align__(16) uint4 wlds[1024];      // 16KB: frag f at [f*64+lane]
  __shared__ __align__(16) float cst[4][16][68];  // 17.4KB: per-wave C transpose
  __shared__ float pacc[64];
  int bid = blockIdx.x;
  const unsigned short *A, *X, *Wlb, *Wrb;
  const float* bias;
  unsigned short* Y;
  int N;
  if (bid < g1) {
    A = A1; X = X1; Wlb = Wl1; Wrb = Wr1; bias = bias1; Y = Y1; N = N1;
  } else {
    bid -= g1;
    A = A2; X = X2; Wlb = Wl2; Wrb = Wr2; bias = bias2; Y = Y2; N = N2;
  }
  int t = threadIdx.x;
  if (lastLayer && t < 64) pacc[t] = 0.f;

  // ---- coalesced weight staging with frag permutation ----
#pragma unroll
  for (int p = 0; p < 4; ++p) {
    int c = p * 256 + t;
    int op = c >> 9;
    int c9 = c & 511;
    int row = c9 >> 3;
    int ch8 = c9 & 7;
    const unsigned short* W = op ? Wrb : Wlb;
    uint4 v = *(const uint4*)(W + row * 64 + ch8 * 8);
    int f = op * 8 + (ch8 >> 2) * 4 + (row >> 4);
    wlds[f * 64 + (ch8 & 3) * 16 + (row & 15)] = v;
  }

  int wid = t >> 6, lane = t & 63;
  int lr = lane & 15;  // row within A/B frags; col (=h low) within C
  int kg = lane >> 4;  // k-subgroup 0..3
  int w0 = bid * 256 + wid * 64;  // this wave's first row

  float bias_r[4];
#pragma unroll
  for (int nt = 0; nt < 4; ++nt) bias_r[nt] = bias[nt * 16 + lr];

  __syncthreads();  // weights visible

  union UB { uint4 u; bh8 v; };
  // all 16 weight fragments -> registers, reused by all 4 subtiles
  UB bl0[4], bl1[4], br0[4], br1[4];
#pragma unroll
  for (int nt = 0; nt < 4; ++nt) {
    bl0[nt].u = wlds[(0 + nt) * 64 + lane];   // Wl, k 0..31
    bl1[nt].u = wlds[(4 + nt) * 64 + lane];   // Wl, k 32..63
    br0[nt].u = wlds[(8 + nt) * 64 + lane];   // Wr, k 0..31
    br1[nt].u = wlds[(12 + nt) * 64 + lane];  // Wr, k 32..63
  }

  // prefetch subtile 0
  int mr = min(w0 + lr, N - 1);
  const bh8* ar = (const bh8*)(A + (size_t)mr * 64);
  const bh8* xr = (const bh8*)(X + (size_t)mr * 64);
  bh8 a0 = ar[kg], a1 = ar[4 + kg], x0 = xr[kg], x1 = xr[4 + kg];

  float psum[4] = {0.f, 0.f, 0.f, 0.f};

#pragma unroll
  for (int sub = 0; sub < 4; ++sub) {
    bh8 na0 = a0, na1 = a1, nx0 = x0, nx1 = x1;
    if (sub < 3) {  // prefetch next subtile under this one's MFMAs
      int mrn = min(w0 + (sub + 1) * 16 + lr, N - 1);
      const bh8* arn = (const bh8*)(A + (size_t)mrn * 64);
      const bh8* xrn = (const bh8*)(X + (size_t)mrn * 64);
      na0 = arn[kg]; na1 = arn[4 + kg]; nx0 = xrn[kg]; nx1 = xrn[4 + kg];
    }
    fx4 acc[4];
#pragma unroll
    for (int nt = 0; nt < 4; ++nt) acc[nt] = (fx4){0.f, 0.f, 0.f, 0.f};
#pragma unroll
    for (int nt = 0; nt < 4; ++nt)
      acc[nt] = __builtin_amdgcn_mfma_f32_16x16x32_bf16(a0, bl0[nt].v, acc[nt], 0, 0, 0);
#pragma unroll
    for (int nt = 0; nt < 4; ++nt)
      acc[nt] = __builtin_amdgcn_mfma_f32_16x16x32_bf16(a1, bl1[nt].v, acc[nt], 0, 0, 0);
#pragma unroll
    for (int nt = 0; nt < 4; ++nt)
      acc[nt] = __builtin_amdgcn_mfma_f32_16x16x32_bf16(x0, br0[nt].v, acc[nt], 0, 0, 0);
#pragma unroll
    for (int nt = 0; nt < 4; ++nt)
      acc[nt] = __builtin_amdgcn_mfma_f32_16x16x32_bf16(x1, br1[nt].v, acc[nt], 0, 0, 0);

    int mbase = w0 + sub * 16;
    if (!lastLayer) {
      // stage C (bias added) into per-wave tile: row = kg*4+j, col = h
#pragma unroll
      for (int nt = 0; nt < 4; ++nt)
#pragma unroll
        for (int j = 0; j < 4; ++j)
          cst[wid][kg * 4 + j][nt * 16 + lr] = acc[nt][j] + bias_r[nt];
      // per-wave tile readback (R11-proven; same wave, no barrier needed)
#pragma unroll
      for (int s = 0; s < 2; ++s) {
        int idx = lane + 64 * s;  // 16 rows x 8 chunks of 8 h
        int r = idx >> 3, c = idx & 7;
        float4 v0 = *(const float4*)&cst[wid][r][c * 8];
        float4 v1 = *(const float4*)&cst[wid][r][c * 8 + 4];
        uint4 pk;
        pk.x = (unsigned int)f2bf(v0.x) | ((unsigned int)f2bf(v0.y) << 16);
        pk.y = (unsigned int)f2bf(v0.z) | ((unsigned int)f2bf(v0.w) << 16);
        pk.z = (unsigned int)f2bf(v1.x) | ((unsigned int)f2bf(v1.y) << 16);
        pk.w = (unsigned int)f2bf(v1.z) | ((unsigned int)f2bf(v1.w) << 16);
        int m = mbase + r;
        if (m < N) ((uint4*)(Y + (size_t)m * 64))[c] = pk;
      }
    } else {
      // pooled-only epilogue: no Y write
#pragma unroll
      for (int nt = 0; nt < 4; ++nt) {
#pragma unroll
        for (int j = 0; j < 4; ++j) {
          int m = mbase + kg * 4 + j;
          if (m < N) psum[nt] += acc[nt][j] + bias_r[nt];
        }
      }
    }
    a0 = na0; a1 = na1; x0 = nx0; x1 = nx1;
  }

  if (lastLayer) {
#pragma unroll
    for (int nt = 0; nt < 4; ++nt) atomicAdd(&pacc[nt * 16 + lr], psum[nt]);
    __syncthreads();
    if (t < 64) atomicAdd(&pooled[t], pacc[t]);
  }
}

// ---------------- final linear ----------------

__global__ void final_kernel(const float* __restrict__ pooled, const float* __restrict__ linW,
                             const float* __restrict__ linb, float* __restrict__ out, float invM) {
  int t = threadIdx.x;  // 64 threads
  float v = pooled[t] * invM * linW[t];
#pragma unroll
  for (int o = 32; o > 0; o >>= 1) v += __shfl_down(v, o, 64);
  if (t == 0) out[0] = v + linb[0];
}

// ---------------- launch ----------------

extern "C" void kernel_launch(void* const* d_in, const int* in_sizes, int n_in,
                              void* d_out, int out_size, void* d_ws, size_t ws_size,
                              hipStream_t stream) {
  const float* x_source = (const float*)d_in[0];
  const float* x_target = (const float*)d_in[1];
  float* scratchA = (float*)d_in[2];  // edge_attr_s2t: 12.8M floats, unused input
  float* scratchB = (float*)d_in[3];  // edge_attr_t2s: 12.8M floats, unused input
  const float* W_l_s2t = (const float*)d_in[4];
  const float* b_s2t   = (const float*)d_in[5];
  const float* W_r_s2t = (const float*)d_in[6];
  const float* W_l_t2s = (const float*)d_in[7];
  const float* b_t2s   = (const float*)d_in[8];
  const float* W_r_t2s = (const float*)d_in[9];
  const float* lin_W   = (const float*)d_in[10];
  const float* lin_b   = (const float*)d_in[11];
  const int* ei_s2t    = (const int*)d_in[12];
  const int* ei_t2s    = (const int*)d_in[13];

  const int NS = in_sizes[0] / FDIM;
  const int NT = in_sizes[1] / FDIM;
  const int E  = in_sizes[12] / 2;
  const int L  = in_sizes[4] / (FDIM * FDIM);
  const size_t NF = (size_t)NS * FDIM;        // 6.4M elems
  const size_t WN = (size_t)L * FDIM * FDIM;  // per weight array, elems

  // scratchA: S0, T0 (bf16 NF), Wb x4, csr_t, csr_s, inv_t, inv_s, off_t, off_s
  unsigned short* S0 = (unsigned short*)scratchA;          // NF bf16
  unsigned short* T0 = S0 + NF;                            // NF bf16
  unsigned short* WbLs2t = T0 + NF;                        // L*4096 bf16
  unsigned short* WbRs2t = WbLs2t + WN;
  unsigned short* WbLt2s = WbRs2t + WN;
  unsigned short* WbRt2s = WbLt2s + WN;
  int*   csr_t  = (int*)(WbRt2s + WN);        // E
  int*   csr_s  = csr_t + E;                  // E
  float* inv_t  = (float*)(csr_s + E);        // NS
  float* inv_s  = inv_t + NS;                 // NS
  int*   off_t  = (int*)(inv_s + NS);         // NS+1
  int*   off_s  = off_t + NS + 1;             // NS+1

  const int NB_T = (NT + 255) >> 8;
  const int NB_S = (NS + 255) >> 8;
  const int B    = (E + 4095) >> 12;

  // scratchB: S1, T1, binned_t, binned_s, H_t, H_s, tot/boff x2
  unsigned short* S1 = (unsigned short*)scratchB;          // NF bf16
  unsigned short* T1 = S1 + NF;                            // NF bf16
  int* binned_t = (int*)(T1 + NF);                         // E
  int* binned_s = binned_t + E;                            // E
  int* H_t      = binned_s + E;                            // B*NB_T
  int* H_s      = H_t + (size_t)B * NB_T;                  // B*NB_S
  int* tot_t    = H_s + (size_t)B * NB_S;                  // 512
  int* boff_t   = tot_t + 512;                             // 512
  int* tot_s    = boff_t + 512;                            // 512
  int* boff_s   = tot_s + 512;                             // 512
  // A_s aliases binned_t+binned_s (dead after build; 2*E*4 == NF*2 bytes)
  unsigned short* As = (unsigned short*)binned_t;

  // d_ws: A_t (bf16 NF) + pooled
  unsigned short* At = (unsigned short*)d_ws;
  float* pooled = (float*)(At + NF);

  const int* src_s2t = ei_s2t;
  const int* dst_s2t = ei_s2t + E;
  const int* src_t2s = ei_t2s;
  const int* dst_t2s = ei_t2s + E;

  // --- CSR build, both directions per pass ---
  hist2_kernel<<<2 * B, 256, 0, stream>>>(dst_s2t, H_t, NB_T, dst_t2s, H_s, NB_S, E, B);
  colscan2_kernel<<<NB_T + NB_S, 256, 0, stream>>>(H_t, tot_t, NB_T, H_s, tot_s, NB_S, B);
  totscan2_kernel<<<2, 256, 0, stream>>>(tot_t, boff_t, NB_T, tot_s, boff_s, NB_S);
  bin2_kernel<<<2 * B, 256, 0, stream>>>(src_s2t, dst_s2t, H_t, boff_t, binned_t, NB_T,
                                         src_t2s, dst_t2s, H_s, boff_s, binned_s, NB_S, E, B);
  build2_kernel<<<NB_T + NB_S, 256, 0, stream>>>(binned_t, boff_t, off_t, csr_t, inv_t, NT, NB_T,
                                                 binned_s, boff_s, off_s, csr_s, inv_s, NS, NB_S, E);

  // --- bf16 packs: features (1 dispatch) + all weights (1 dispatch) ---
  int n4F = (int)(NF / 4);
  int gP = (n4F + 255) / 256;
  pack2_kernel<<<2 * gP, 256, 0, stream>>>(x_source, S0, x_target, T0, n4F, gP);
  int n4W = (int)(WN / 4);
  int gW = (n4W + 255) / 256;
  pack4_kernel<<<4 * gW, 256, 0, stream>>>(W_l_s2t, WbLs2t, W_r_s2t, WbRs2t,
                                           W_l_t2s, WbLt2s, W_r_t2s, WbRt2s, n4W, gW);

  hipMemsetAsync(pooled, 0, 64 * 4, stream);

  unsigned short* xs_in = S0;
  unsigned short* xt_in = T0;
  unsigned short* xs_out = S1;
  unsigned short* xt_out = T1;

  int aT = (NT + 15) / 16;  // agg4 blocks (16 nodes/block)
  int aS = (NS + 15) / 16;
  int gT3 = (NT + 255) / 256;  // fgemm3 blocks (256 rows/block)
  int gS3 = (NS + 255) / 256;

  for (int l = 0; l < L; ++l) {
    const unsigned short* Wl1 = WbLs2t + (size_t)l * 4096;
    const unsigned short* Wr1 = WbRs2t + (size_t)l * 4096;
    const float* bb1 = b_s2t + (size_t)l * 64;
    const unsigned short* Wl2 = WbLt2s + (size_t)l * 4096;
    const unsigned short* Wr2 = WbRt2s + (size_t)l * 4096;
    const float* bb2 = b_t2s + (size_t)l * 64;
    int last = (l == L - 1) ? 1 : 0;

    // A_t = mean_agg(xs_in) over s2t CSR; A_s = mean_agg(xt_in) over t2s CSR
    agg4_kernel<<<aT + aS, 256, 0, stream>>>(xs_in, off_t, csr_t, inv_t, At, NT, aT,
                                             xt_in, off_s, csr_s, inv_s, As, NS);
    // xt_out = A_t@Wl1^T + xt_in@Wr1^T + b1 ; xs_out = A_s@Wl2^T + xs_in@Wr2^T + b2
    fgemm3_kernel<<<gT3 + gS3, 256, 0, stream>>>(At, xt_in, Wl1, Wr1, bb1, xt_out, NT,
                                                 As, xs_in, Wl2, Wr2, bb2, xs_out, NS,
                                                 gT3, pooled, last);

    unsigned short* ts = xs_in; xs_in = xs_out; xs_out = ts;
    unsigned short* tt = xt_in; xt_in = xt_out; xt_out = tt;
  }

  final_kernel<<<1, 64, 0, stream>>>(pooled, lin_W, lin_b, (float*)d_out,
                                     1.0f / (float)(NS + NT));
}